// Round 1
// baseline (2196.299 us; speedup 1.0000x reference)
//
#include <hip/hip_runtime.h>
#include <hip/hip_bf16.h>

namespace {
constexpr int Bn = 2, Cn = 64, Dn = 16, Hn = 64, Wn = 64;
constexpr int Gn = 2, Kn = 27, GCn = 32;
constexpr int DHW = Dn * Hn * Wn;                 // 65536
constexpr int PDn = Dn + 2, PHn = Hn + 2, PWn = Wn + 2;
constexpr int PADVOL = PDn * PHn * PWn;           // 78408
constexpr int OCn = 216;                          // 162 off + 54 mask channels
constexpr int RPG = 24;                           // conv out-channels per block (9 groups)
constexpr float EPS = 1e-5f;

constexpr size_t XPAD_B  = (size_t)Bn * Cn * PADVOL * 4;   // 40,144,896 (also reused for `sampled`)
constexpr size_t WC_OFF  = XPAD_B;
constexpr size_t WC_B    = (size_t)27 * Cn * OCn * 4;      // 1,492,992
constexpr size_t WV_OFF  = WC_OFF + WC_B;
constexpr size_t WV_B    = (size_t)Cn * Cn * 4;
constexpr size_t CONV_OFF = WV_OFF + WV_B;                 // bf16 conv out
constexpr size_t CONV_B  = (size_t)Bn * OCn * DHW * 2;     // 56,623,104
constexpr size_t V_OFF   = CONV_OFF + CONV_B;
constexpr size_t V_B     = (size_t)Bn * Gn * DHW * GCn * 4; // 33,554,432
constexpr size_t STAT_OFF = V_OFF + V_B;                   // 131,831,808 (+1KB)
}

// ---- fold pre 1x1 into conv weights and value projection ----
// Wc layout: [tap][c][oc]  (oc contiguous -> scalar dwordx loads in conv)
__global__ __launch_bounds__(256) void fold_weights(
    const float* __restrict__ pre_w, const float* __restrict__ in_proj_w,
    const float* __restrict__ off_w, const float* __restrict__ mask_w,
    float* __restrict__ Wc, float* __restrict__ Wv) {
  int i = blockIdx.x * 256 + threadIdx.x;
  if (i < Cn * Cn) {
    int o = i >> 6, c = i & 63;
    float s = 0.f;
    for (int cp = 0; cp < Cn; ++cp) s += in_proj_w[o * Cn + cp] * pre_w[cp * Cn + c];
    Wv[i] = s;
    return;
  }
  int j = i - Cn * Cn;
  if (j >= 27 * Cn * OCn) return;
  int oc = j % OCn; int r = j / OCn; int c = r & 63; int tap = r >> 6;
  const float* cw = (oc < 162) ? (off_w + oc * Cn * 27) : (mask_w + (oc - 162) * Cn * 27);
  float s = 0.f;
  for (int cp = 0; cp < Cn; ++cp) s += cw[cp * 27 + tap] * pre_w[cp * Cn + c];
  Wc[j] = s;
}

// ---- zero-padded copy of x: [B,C,18,66,66] ----
__global__ __launch_bounds__(256) void pad_x(const float* __restrict__ x,
                                             float* __restrict__ xpad) {
  int i = blockIdx.x * 256 + threadIdx.x;            // exactly B*C*PADVOL threads
  int wx = i % PWn; int r = i / PWn;
  int hy = r % PHn; r /= PHn;
  int dz = r % PDn; int bc = r / PDn;
  float val = 0.f;
  if (dz >= 1 && dz <= Dn && hy >= 1 && hy <= Hn && wx >= 1 && wx <= Wn)
    val = x[bc * DHW + ((dz - 1) * Hn + (hy - 1)) * Wn + (wx - 1)];
  xpad[i] = val;
}

// ---- value projection v = (in_proj_w @ pre_w) @ x + b, layout [b,g,p,32] ----
__global__ __launch_bounds__(256) void vproj(
    const float* __restrict__ x, const float* __restrict__ Wv,
    const float* __restrict__ vb, float* __restrict__ v) {
  int p = blockIdx.x * 256 + threadIdx.x;
  int b = blockIdx.y;
  const float* xb = x + b * Cn * DHW;
  float xv[Cn];
#pragma unroll
  for (int c = 0; c < Cn; ++c) xv[c] = xb[c * DHW + p];
#pragma unroll 1
  for (int g = 0; g < Gn; ++g) {
    float vo[GCn];
#pragma unroll
    for (int j = 0; j < GCn; ++j) {
      int o = g * GCn + j;
      float s = vb[o];
#pragma unroll
      for (int c = 0; c < Cn; ++c) s += Wv[o * Cn + c] * xv[c];
      vo[j] = s;
    }
    float4* dst = (float4*)(v + ((b * Gn + g) * DHW + p) * GCn);
#pragma unroll
    for (int q = 0; q < 8; ++q)
      dst[q] = make_float4(vo[4 * q], vo[4 * q + 1], vo[4 * q + 2], vo[4 * q + 3]);
  }
}

// ---- 3x3x3 conv (216 out channels, folded weights), thread = position, block = 24 oc ----
__global__ __launch_bounds__(256) void conv3x3(
    const float* __restrict__ xpad, const float* __restrict__ Wc,
    const float* __restrict__ off_b, const float* __restrict__ mask_b,
    __hip_bfloat16* __restrict__ convout) {
  int p = blockIdx.x * 256 + threadIdx.x;
  int ocg = blockIdx.y, b = blockIdx.z;
  int w = p & 63, h = (p >> 6) & 63, d = p >> 12;
  float acc[RPG];
#pragma unroll
  for (int j = 0; j < RPG; ++j) {
    int oc = ocg * RPG + j;
    acc[j] = (oc < 162) ? off_b[oc] : mask_b[oc - 162];
  }
  const float* xb = xpad + b * Cn * PADVOL;
#pragma unroll 1
  for (int tap = 0; tap < 27; ++tap) {
    int dd = tap / 9, rem = tap - dd * 9, dh = rem / 3, dw = rem - (rem / 3) * 3;
    const float* xc = xb + ((d + dd) * PHn + (h + dh)) * PWn + (w + dw);
    const float* wr = Wc + tap * Cn * OCn + ocg * RPG;
#pragma unroll 4
    for (int c = 0; c < Cn; ++c) {
      float xv = xc[c * PADVOL];
      const float* wp = wr + c * OCn;
#pragma unroll
      for (int j = 0; j < RPG; ++j) acc[j] += wp[j] * xv;
    }
  }
  int ob = (b * OCn + ocg * RPG) * DHW + p;
#pragma unroll
  for (int j = 0; j < RPG; ++j)
    convout[ob + j * DHW] = __float2bfloat16(acc[j]);
}

// ---- deformable trilinear sampling + fused mask softmax; out layout [b,g,p,32] ----
__global__ __launch_bounds__(256) void dcn_sample(
    const __hip_bfloat16* __restrict__ convout, const float* __restrict__ v,
    float* __restrict__ sampled) {
  int p = blockIdx.x * 256 + threadIdx.x;
  int bg = blockIdx.y;
  int b = bg >> 1, g = bg & 1;
  int w = p & 63, h = (p >> 6) & 63, d = p >> 12;
  const __hip_bfloat16* cb = convout + b * OCn * DHW;
  const __hip_bfloat16* cm = cb + (162 + g * Kn) * DHW;   // mask logits
  const __hip_bfloat16* cof = cb + g * Kn * 3 * DHW;      // offsets
  float mx = -1e30f;
#pragma unroll 1
  for (int k = 0; k < Kn; ++k) mx = fmaxf(mx, __bfloat162float(cm[k * DHW + p]));
  float msum = 0.f;
#pragma unroll 1
  for (int k = 0; k < Kn; ++k) msum += __expf(__bfloat162float(cm[k * DHW + p]) - mx);
  float rs = 1.f / msum;
  float acc[GCn];
#pragma unroll
  for (int q = 0; q < GCn; ++q) acc[q] = 0.f;
  const float* vg = v + bg * DHW * GCn;
#pragma unroll 1
  for (int k = 0; k < Kn; ++k) {
    float offd = __bfloat162float(cof[(k * 3 + 0) * DHW + p]);
    float offh = __bfloat162float(cof[(k * 3 + 1) * DHW + p]);
    float offw = __bfloat162float(cof[(k * 3 + 2) * DHW + p]);
    float pd = (float)(d + (k / 9) - 1) + offd * 0.5f;    // AXIS=(0.5,1,1)
    float ph = (float)(h + ((k / 3) % 3) - 1) + offh;
    float pw = (float)(w + (k % 3) - 1) + offw;
    float fd = floorf(pd), fh = floorf(ph), fw = floorf(pw);
    float td = pd - fd, th = ph - fh, tw = pw - fw;
    int d0 = (int)fd, h0 = (int)fh, w0 = (int)fw;
    float mk = __expf(__bfloat162float(cm[k * DHW + p]) - mx) * rs;
#pragma unroll
    for (int dd = 0; dd < 2; ++dd) {
      int di = d0 + dd;
      float wd = (dd ? td : 1.f - td) * mk;
#pragma unroll
      for (int hh = 0; hh < 2; ++hh) {
        int hi = h0 + hh;
        float whf = (hh ? th : 1.f - th) * wd;
#pragma unroll
        for (int ww = 0; ww < 2; ++ww) {
          int wi = w0 + ww;
          float wt = (ww ? tw : 1.f - tw) * whf;
          bool valid = (di >= 0) & (di < Dn) & (hi >= 0) & (hi < Hn) & (wi >= 0) & (wi < Wn);
          if (valid) {
            const float4* src = (const float4*)(vg + ((di * Hn + hi) * Wn + wi) * GCn);
#pragma unroll
            for (int q = 0; q < 8; ++q) {
              float4 s4 = src[q];
              acc[4 * q + 0] += wt * s4.x; acc[4 * q + 1] += wt * s4.y;
              acc[4 * q + 2] += wt * s4.z; acc[4 * q + 3] += wt * s4.w;
            }
          }
        }
      }
    }
  }
  float4* dst = (float4*)(sampled + (bg * DHW + p) * GCn);
#pragma unroll
  for (int q = 0; q < 8; ++q)
    dst[q] = make_float4(acc[4 * q], acc[4 * q + 1], acc[4 * q + 2], acc[4 * q + 3]);
}

// ---- out_proj: t[b,c,p] = out_proj_w @ sampled + b (t lives in d_out as scratch) ----
__global__ __launch_bounds__(256) void outproj(
    const float* __restrict__ sampled, const float* __restrict__ Wout,
    const float* __restrict__ ob, float* __restrict__ t) {
  int p = blockIdx.x * 256 + threadIdx.x;
  int b = blockIdx.y;
  float sv[Cn];
#pragma unroll
  for (int g = 0; g < Gn; ++g) {
    const float4* src = (const float4*)(sampled + ((b * Gn + g) * DHW + p) * GCn);
#pragma unroll
    for (int q = 0; q < 8; ++q) {
      float4 s4 = src[q];
      sv[g * GCn + 4 * q + 0] = s4.x; sv[g * GCn + 4 * q + 1] = s4.y;
      sv[g * GCn + 4 * q + 2] = s4.z; sv[g * GCn + 4 * q + 3] = s4.w;
    }
  }
#pragma unroll 1
  for (int o = 0; o < Cn; ++o) {
    float s = ob[o];
#pragma unroll
    for (int c = 0; c < Cn; ++c) s += Wout[o * Cn + c] * sv[c];
    t[(b * Cn + o) * DHW + p] = s;
  }
}

// ---- per-(b,c) instance-norm stats over DHW ----
__global__ __launch_bounds__(256) void stats_k(const float* __restrict__ t,
                                               float* __restrict__ stat) {
  int bc = blockIdx.x;
  const float* tc = t + bc * DHW;
  float s = 0.f, ss = 0.f;
  for (int i = threadIdx.x; i < DHW; i += 256) {
    float xv = tc[i]; s += xv; ss += xv * xv;
  }
#pragma unroll
  for (int o = 32; o > 0; o >>= 1) { s += __shfl_down(s, o); ss += __shfl_down(ss, o); }
  __shared__ float ls[4], lss[4];
  int wid = threadIdx.x >> 6;
  if ((threadIdx.x & 63) == 0) { ls[wid] = s; lss[wid] = ss; }
  __syncthreads();
  if (threadIdx.x == 0) {
    float S = ls[0] + ls[1] + ls[2] + ls[3];
    float SS = lss[0] + lss[1] + lss[2] + lss[3];
    float mu = S / (float)DHW;
    float var = SS / (float)DHW - mu * mu;
    stat[bc * 2 + 0] = mu;
    stat[bc * 2 + 1] = rsqrtf(var + EPS);
  }
}

// ---- norm + gelu + post 1x1 + gated residual (t and out alias d_out; per-thread column) ----
__global__ __launch_bounds__(256) void finalk(
    const float* t, const float* __restrict__ x, const float* __restrict__ stat,
    const float* __restrict__ gamma, const float* __restrict__ beta,
    const float* __restrict__ Wpost, const float* __restrict__ gate, float* out) {
  int p = blockIdx.x * 256 + threadIdx.x;
  int b = blockIdx.y;
  float sg = 1.f / (1.f + __expf(-gate[0]));
  float nv[Cn];
#pragma unroll
  for (int c = 0; c < Cn; ++c) {
    float mu = stat[(b * Cn + c) * 2 + 0];
    float rstd = stat[(b * Cn + c) * 2 + 1];
    float yv = (t[(b * Cn + c) * DHW + p] - mu) * rstd * gamma[c] + beta[c];
    float u = 0.7978845608028654f * (yv + 0.044715f * yv * yv * yv);
    float e = __expf(2.f * u);
    float th = 1.f - 2.f / (e + 1.f);                 // tanh(u), saturates safely
    nv[c] = 0.5f * yv * (1.f + th);
  }
#pragma unroll 1
  for (int o = 0; o < Cn; ++o) {
    float s = 0.f;
#pragma unroll
    for (int c = 0; c < Cn; ++c) s += Wpost[o * Cn + c] * nv[c];
    int i = (b * Cn + o) * DHW + p;
    out[i] = x[i] + sg * s;
  }
}

extern "C" void kernel_launch(void* const* d_in, const int* in_sizes, int n_in,
                              void* d_out, int out_size, void* d_ws, size_t ws_size,
                              hipStream_t stream) {
  const float* x          = (const float*)d_in[0];
  const float* gate       = (const float*)d_in[1];
  const float* pre_w      = (const float*)d_in[2];
  const float* post_w     = (const float*)d_in[3];
  const float* in_proj_w  = (const float*)d_in[4];
  const float* in_proj_b  = (const float*)d_in[5];
  const float* out_proj_w = (const float*)d_in[6];
  const float* out_proj_b = (const float*)d_in[7];
  const float* off_w      = (const float*)d_in[8];
  const float* off_b      = (const float*)d_in[9];
  const float* mask_w     = (const float*)d_in[10];
  const float* mask_b     = (const float*)d_in[11];
  const float* in_gamma   = (const float*)d_in[12];
  const float* in_beta    = (const float*)d_in[13];

  char* ws = (char*)d_ws;
  float* xpad    = (float*)(ws + 0);
  float* sampled = (float*)(ws + 0);                 // reuses xpad region (conv done by then)
  float* Wc      = (float*)(ws + WC_OFF);
  float* Wv      = (float*)(ws + WV_OFF);
  __hip_bfloat16* convout = (__hip_bfloat16*)(ws + CONV_OFF);
  float* v       = (float*)(ws + V_OFF);
  float* stat    = (float*)(ws + STAT_OFF);
  float* t   = (float*)d_out;                        // pre-norm tensor scratch
  float* out = (float*)d_out;

  int foldN = (Cn * Cn + 27 * Cn * OCn + 255) / 256;        // 1474
  fold_weights<<<foldN, 256, 0, stream>>>(pre_w, in_proj_w, off_w, mask_w, Wc, Wv);
  pad_x<<<(Bn * Cn * PADVOL) / 256, 256, 0, stream>>>(x, xpad);
  vproj<<<dim3(DHW / 256, Bn), 256, 0, stream>>>(x, Wv, in_proj_b, v);
  conv3x3<<<dim3(DHW / 256, OCn / RPG, Bn), 256, 0, stream>>>(xpad, Wc, off_b, mask_b, convout);
  dcn_sample<<<dim3(DHW / 256, Bn * Gn), 256, 0, stream>>>(convout, v, sampled);
  outproj<<<dim3(DHW / 256, Bn), 256, 0, stream>>>(sampled, out_proj_w, out_proj_b, t);
  stats_k<<<Bn * Cn, 256, 0, stream>>>(t, stat);
  finalk<<<dim3(DHW / 256, Bn), 256, 0, stream>>>(t, x, stat, in_gamma, in_beta,
                                                  post_w, gate, out);
}

// Round 2
// 1178.902 us; speedup vs baseline: 1.8630x; 1.8630x over previous
//
#include <hip/hip_runtime.h>
#include <hip/hip_bf16.h>

typedef short short8 __attribute__((ext_vector_type(8)));
typedef float f32x4 __attribute__((ext_vector_type(4)));

namespace {
constexpr int Bn = 2, Cn = 64, Dn = 16, Hn = 64, Wn = 64;
constexpr int Gn = 2, Kn = 27, GCn = 32;
constexpr int DHW = Dn * Hn * Wn;                 // 65536
constexpr int OCn = 216;                          // 162 off + 54 mask
constexpr int PD = 18, PH = 66, PW = 66;
constexpr float EPS = 1e-5f;

// patch: 3d x 4h x 66w rows of 128B (64ch bf16)
constexpr int PROWS = 12 * 66;                    // 792
constexpr int PATCH_B = PROWS * 128;              // 101376
constexpr int ABUF_B = 16384;                     // 256 rows x 32 k x 2B

constexpr size_t XPADH_OFF = 0;
constexpr size_t XPADH_B   = (size_t)Bn * PD * PH * PW * Cn * 2;   // 20,072,448
constexpr size_t WFRAG_OFF = XPADH_OFF + XPADH_B;
constexpr size_t WFRAG_B   = (size_t)54 * 16 * 64 * 16;            // 884,736
constexpr size_t WV_OFF    = WFRAG_OFF + WFRAG_B;
constexpr size_t WV_B      = 64 * 64 * 4;
constexpr size_t CONV_OFF  = WV_OFF + WV_B;
constexpr size_t CONV_B    = (size_t)Bn * OCn * DHW * 2;           // 56,623,104
constexpr size_t V_OFF     = CONV_OFF + CONV_B;
constexpr size_t V_B       = (size_t)Bn * Gn * DHW * GCn * 4;      // 33,554,432
constexpr size_t SAMP_OFF  = V_OFF + V_B;
constexpr size_t SAMP_B    = (size_t)Bn * Gn * DHW * GCn * 2;      // 16,777,216
constexpr size_t STAT_OFF  = SAMP_OFF + SAMP_B;
}

__device__ inline float b2f(short s) {
  union { float f; unsigned u; } x; x.u = ((unsigned)(unsigned short)s) << 16; return x.f;
}
__device__ inline short f2b(float f) {
  __hip_bfloat16 h = __float2bfloat16(f);
  union { __hip_bfloat16 h; short s; } x; x.h = h; return x.s;
}

// ---- zero-fill padded input volume ----
__global__ __launch_bounds__(256) void zerofill(uint4* __restrict__ p, int n16) {
  int i = blockIdx.x * 256 + threadIdx.x;
  if (i < n16) p[i] = make_uint4(0, 0, 0, 0);
}

// ---- transpose-pad x [b,c,d,h,w] f32 -> xpadh [b,dz,hy,wx,c] bf16 (interior) ----
__device__ inline int tp_addr(int hh, int w, int c) {
  return (hh * 64 + w) * 128 + (((c >> 3) ^ (w & 7)) << 4) +
         (((((c & 7) >> 1) ^ ((w >> 3) & 3))) << 2) + ((c & 1) << 1);
}
__global__ __launch_bounds__(256) void fillpad(const float* __restrict__ x,
                                               __hip_bfloat16* __restrict__ xpadh) {
  __shared__ char lds[8 * 64 * 128];               // 64KB: 8h x 64w x 64c bf16 (swizzled)
  int tid = threadIdx.x;
  int hc = blockIdx.x, d = blockIdx.y, b = blockIdx.z;
  int h0 = hc * 8;
  {
    int cq = tid >> 6, w = tid & 63;
#pragma unroll 1
    for (int cc = 0; cc < 16; ++cc) {
      int c = cc * 4 + cq;
      const float* xr = x + ((size_t)(b * 64 + c)) * DHW + d * 4096 + w;
#pragma unroll
      for (int hh = 0; hh < 8; ++hh) {
        float v = xr[(h0 + hh) * 64];
        *(short*)(lds + tp_addr(hh, w, c)) = f2b(v);
      }
    }
  }
  __syncthreads();
  {
    int c = tid & 63, w4 = tid >> 6;
    __hip_bfloat16* ob = xpadh + (size_t)b * (PD * PH * PW * 64);
#pragma unroll 1
    for (int hh = 0; hh < 8; ++hh) {
      size_t rowb = (((size_t)(d + 1) * 66) + (h0 + hh + 1)) * 66;
#pragma unroll
      for (int wq = 0; wq < 16; ++wq) {
        int w = wq * 4 + w4;
        short v = *(const short*)(lds + tp_addr(hh, w, c));
        *(short*)(ob + (rowb + w + 1) * 64 + c) = v;
      }
    }
  }
}

// ---- fold pre 1x1 into conv weights (MFMA fragment order) and value projection ----
__global__ __launch_bounds__(256) void fold_weights(
    const float* __restrict__ pre_w, const float* __restrict__ in_proj_w,
    const float* __restrict__ off_w, const float* __restrict__ mask_w,
    short8* __restrict__ Wfrag, float* __restrict__ Wv) {
  int i = blockIdx.x * 256 + threadIdx.x;
  if (i < 64 * 64) {
    int o = i >> 6, c = i & 63;
    float s = 0.f;
    for (int cp = 0; cp < 64; ++cp) s += in_proj_w[o * 64 + cp] * pre_w[cp * 64 + c];
    Wv[i] = s;
    return;
  }
  int t = i - 64 * 64;
  if (t >= 54 * 16 * 64) return;
  int l = t & 63; int rest = t >> 6;
  int mt = rest & 15; int ks = rest >> 4;
  int oc = mt * 16 + (l & 15);
  int tap = ks >> 1;
  int c0 = (ks & 1) * 32 + (l >> 4) * 8;
  float vals[8] = {0.f, 0.f, 0.f, 0.f, 0.f, 0.f, 0.f, 0.f};
  if (oc < OCn) {
    const float* cw = (oc < 162) ? (off_w + (size_t)oc * 64 * 27)
                                 : (mask_w + (size_t)(oc - 162) * 64 * 27);
#pragma unroll 1
    for (int cp = 0; cp < 64; ++cp) {
      float wv = cw[cp * 27 + tap];
      const float* pr = pre_w + cp * 64 + c0;
#pragma unroll
      for (int j = 0; j < 8; ++j) vals[j] += wv * pr[j];
    }
  }
  short8 o8;
#pragma unroll
  for (int j = 0; j < 8; ++j) o8[j] = f2b(vals[j]);
  Wfrag[t] = o8;
}

// ---- value projection v = (in_proj_w @ pre_w) @ x + b, layout [b,g,p,32] f32 ----
__global__ __launch_bounds__(256) void vproj(
    const float* __restrict__ x, const float* __restrict__ Wv,
    const float* __restrict__ vb, float* __restrict__ v) {
  int p = blockIdx.x * 256 + threadIdx.x;
  int b = blockIdx.y;
  const float* xb = x + (size_t)b * Cn * DHW;
  float xv[Cn];
#pragma unroll
  for (int c = 0; c < Cn; ++c) xv[c] = xb[c * DHW + p];
#pragma unroll 1
  for (int g = 0; g < Gn; ++g) {
    float vo[GCn];
#pragma unroll
    for (int j = 0; j < GCn; ++j) {
      int o = g * GCn + j;
      float s = vb[o];
#pragma unroll
      for (int c = 0; c < Cn; ++c) s += Wv[o * Cn + c] * xv[c];
      vo[j] = s;
    }
    float4* dst = (float4*)(v + ((size_t)(b * Gn + g) * DHW + p) * GCn);
#pragma unroll
    for (int q = 0; q < 8; ++q)
      dst[q] = make_float4(vo[4 * q], vo[4 * q + 1], vo[4 * q + 2], vo[4 * q + 3]);
  }
}

// ---- MFMA implicit-GEMM 3x3x3 conv: M=256(216) oc x N=128 pos, K=1728 ----
__global__ __launch_bounds__(512, 2) void conv_mfma(
    const char* __restrict__ xpadh, const uint4* __restrict__ wfrag,
    const float* __restrict__ off_b, const float* __restrict__ mask_b,
    __hip_bfloat16* __restrict__ convout) {
  __shared__ char lds[PATCH_B + 2 * ABUF_B];       // 134,144 B
  int tid = threadIdx.x;
  int h0 = blockIdx.x * 2, d = blockIdx.y, b = blockIdx.z;

  // stage patch (all 27 taps' B-data), XOR-swizzled rows
  const char* xb = xpadh + (size_t)b * (PD * PH * PW * 128);
  for (int idx = tid; idx < PROWS * 8; idx += 512) {
    int s = idx >> 3, slot = idx & 7;
    int r12 = s / 66, wx = s - r12 * 66;
    int dp = r12 >> 2, hp = r12 & 3;
    const char* g = xb + ((((size_t)(d + dp)) * 66 + (h0 + hp)) * 66 + wx) * 128 + slot * 16;
    uint4 vv = *(const uint4*)g;
    *(uint4*)(lds + s * 128 + ((slot ^ (s & 7)) << 4)) = vv;
  }
  // stage A[0]
  for (int u = tid; u < 1024; u += 512)
    *(uint4*)(lds + PATCH_B + u * 16) = wfrag[u];
  __syncthreads();

  int wid = tid >> 6, l = tid & 63;
  int wm = wid & 3, wn = wid >> 2;                 // M quarter, N half (== h row)
  int lm = l & 15, lk = l >> 4;
  f32x4 acc[4][4];
#pragma unroll
  for (int mt = 0; mt < 4; ++mt)
#pragma unroll
    for (int nt = 0; nt < 4; ++nt) acc[mt][nt] = (f32x4){0.f, 0.f, 0.f, 0.f};

#pragma unroll 1
  for (int ks = 0; ks < 54; ++ks) {
    int cur = ks & 1;
    uint4 st0, st1;
    if (ks < 53) {                                 // issue next A-tile loads early
      st0 = wfrag[(ks + 1) * 1024 + tid];
      st1 = wfrag[(ks + 1) * 1024 + tid + 512];
    }
    int tap = ks >> 1;
    int dd = tap / 9, rem = tap - dd * 9, dh = rem / 3, dw = rem - dh * 3;
    int srow = (dd * 4 + wn + dh) * 66 + dw;
    int uslot = 4 * (ks & 1) + lk;
    short8 bfr[4];
#pragma unroll
    for (int nt = 0; nt < 4; ++nt) {
      int s = srow + nt * 16 + lm;
      bfr[nt] = *(const short8*)(lds + s * 128 + ((uslot ^ (s & 7)) << 4));
    }
    const char* abase = lds + PATCH_B + cur * ABUF_B + (wm * 256 + l) * 16;
    short8 afr[4];
#pragma unroll
    for (int mt = 0; mt < 4; ++mt)
      afr[mt] = *(const short8*)(abase + mt * 1024);
#pragma unroll
    for (int mt = 0; mt < 4; ++mt)
#pragma unroll
      for (int nt = 0; nt < 4; ++nt)
        acc[mt][nt] = __builtin_amdgcn_mfma_f32_16x16x32_bf16(afr[mt], bfr[nt], acc[mt][nt], 0, 0, 0);
    if (ks < 53) {
      char* adst = lds + PATCH_B + (cur ^ 1) * ABUF_B;
      *(uint4*)(adst + tid * 16) = st0;
      *(uint4*)(adst + (tid + 512) * 16) = st1;
    }
    __syncthreads();
  }

  int pbase = d * 4096 + (h0 + wn) * 64;
#pragma unroll
  for (int mt = 0; mt < 4; ++mt) {
    int oc0 = wm * 64 + mt * 16 + lk * 4;
#pragma unroll
    for (int r = 0; r < 4; ++r) {
      int oc = oc0 + r;
      if (oc < OCn) {
        float bias = (oc < 162) ? off_b[oc] : mask_b[oc - 162];
        size_t orow = ((size_t)b * OCn + oc) * DHW + pbase;
#pragma unroll
        for (int nt = 0; nt < 4; ++nt)
          convout[orow + nt * 16 + lm] = __float2bfloat16(acc[mt][nt][r] + bias);
      }
    }
  }
}

// ---- deformable trilinear sampling + fused mask softmax; out bf16 [b,g,p,32] ----
__global__ __launch_bounds__(256) void dcn_sample(
    const __hip_bfloat16* __restrict__ convout, const float* __restrict__ v,
    __hip_bfloat16* __restrict__ sampled) {
  int p = blockIdx.x * 256 + threadIdx.x;
  int bg = blockIdx.y;
  int b = bg >> 1, g = bg & 1;
  int w = p & 63, h = (p >> 6) & 63, d = p >> 12;
  const __hip_bfloat16* cb = convout + (size_t)b * OCn * DHW;
  const __hip_bfloat16* cm = cb + (162 + g * Kn) * (size_t)DHW;
  const __hip_bfloat16* cof = cb + (size_t)g * Kn * 3 * DHW;
  float mx = -1e30f;
#pragma unroll 1
  for (int k = 0; k < Kn; ++k) mx = fmaxf(mx, __bfloat162float(cm[k * (size_t)DHW + p]));
  float msum = 0.f;
#pragma unroll 1
  for (int k = 0; k < Kn; ++k) msum += __expf(__bfloat162float(cm[k * (size_t)DHW + p]) - mx);
  float rs = 1.f / msum;
  float acc[GCn];
#pragma unroll
  for (int q = 0; q < GCn; ++q) acc[q] = 0.f;
  const float* vg = v + (size_t)bg * DHW * GCn;
#pragma unroll 1
  for (int k = 0; k < Kn; ++k) {
    float offd = __bfloat162float(cof[(k * 3 + 0) * (size_t)DHW + p]);
    float offh = __bfloat162float(cof[(k * 3 + 1) * (size_t)DHW + p]);
    float offw = __bfloat162float(cof[(k * 3 + 2) * (size_t)DHW + p]);
    float pd = (float)(d + (k / 9) - 1) + offd * 0.5f;
    float ph = (float)(h + ((k / 3) % 3) - 1) + offh;
    float pw = (float)(w + (k % 3) - 1) + offw;
    float fd = floorf(pd), fh = floorf(ph), fw = floorf(pw);
    float td = pd - fd, th = ph - fh, tw = pw - fw;
    int d0 = (int)fd, h0 = (int)fh, w0 = (int)fw;
    float mk = __expf(__bfloat162float(cm[k * (size_t)DHW + p]) - mx) * rs;
#pragma unroll
    for (int dd = 0; dd < 2; ++dd) {
      int di = d0 + dd;
      float wd = (dd ? td : 1.f - td) * mk;
#pragma unroll
      for (int hh = 0; hh < 2; ++hh) {
        int hi = h0 + hh;
        float whf = (hh ? th : 1.f - th) * wd;
#pragma unroll
        for (int ww = 0; ww < 2; ++ww) {
          int wi = w0 + ww;
          float wt = (ww ? tw : 1.f - tw) * whf;
          bool valid = (di >= 0) & (di < Dn) & (hi >= 0) & (hi < Hn) & (wi >= 0) & (wi < Wn);
          if (valid) {
            const float4* src = (const float4*)(vg + ((size_t)(di * Hn + hi) * Wn + wi) * GCn);
#pragma unroll
            for (int q = 0; q < 8; ++q) {
              float4 s4 = src[q];
              acc[4 * q + 0] += wt * s4.x; acc[4 * q + 1] += wt * s4.y;
              acc[4 * q + 2] += wt * s4.z; acc[4 * q + 3] += wt * s4.w;
            }
          }
        }
      }
    }
  }
  short8* dst = (short8*)(sampled + ((size_t)bg * DHW + p) * GCn);
#pragma unroll
  for (int q = 0; q < 4; ++q) {
    short8 o8;
#pragma unroll
    for (int j = 0; j < 8; ++j) o8[j] = f2b(acc[q * 8 + j]);
    dst[q] = o8;
  }
}

// ---- out_proj (t lives in d_out as scratch) ----
__global__ __launch_bounds__(256) void outproj(
    const __hip_bfloat16* __restrict__ sampled, const float* __restrict__ Wout,
    const float* __restrict__ ob, float* __restrict__ t) {
  int p = blockIdx.x * 256 + threadIdx.x;
  int b = blockIdx.y;
  float sv[Cn];
#pragma unroll
  for (int g = 0; g < Gn; ++g) {
    const short8* src = (const short8*)(sampled) + ((size_t)(b * Gn + g) * DHW + p) * 4;
#pragma unroll
    for (int q = 0; q < 4; ++q) {
      short8 s8 = src[q];
#pragma unroll
      for (int j = 0; j < 8; ++j) sv[g * GCn + q * 8 + j] = b2f(s8[j]);
    }
  }
#pragma unroll 1
  for (int o = 0; o < Cn; ++o) {
    float s = ob[o];
#pragma unroll
    for (int c = 0; c < Cn; ++c) s += Wout[o * Cn + c] * sv[c];
    t[((size_t)b * Cn + o) * DHW + p] = s;
  }
}

// ---- per-(b,c) instance-norm stats ----
__global__ __launch_bounds__(256) void stats_k(const float* __restrict__ t,
                                               float* __restrict__ stat) {
  int bc = blockIdx.x;
  const float* tc = t + (size_t)bc * DHW;
  float s = 0.f, ss = 0.f;
  for (int i = threadIdx.x; i < DHW; i += 256) {
    float xv = tc[i]; s += xv; ss += xv * xv;
  }
#pragma unroll
  for (int o = 32; o > 0; o >>= 1) { s += __shfl_down(s, o); ss += __shfl_down(ss, o); }
  __shared__ float ls[4], lss[4];
  int wid = threadIdx.x >> 6;
  if ((threadIdx.x & 63) == 0) { ls[wid] = s; lss[wid] = ss; }
  __syncthreads();
  if (threadIdx.x == 0) {
    float S = ls[0] + ls[1] + ls[2] + ls[3];
    float SS = lss[0] + lss[1] + lss[2] + lss[3];
    float mu = S / (float)DHW;
    float var = SS / (float)DHW - mu * mu;
    stat[bc * 2 + 0] = mu;
    stat[bc * 2 + 1] = rsqrtf(var + EPS);
  }
}

// ---- norm + gelu + post 1x1 + gated residual ----
__global__ __launch_bounds__(256) void finalk(
    const float* t, const float* __restrict__ x, const float* __restrict__ stat,
    const float* __restrict__ gamma, const float* __restrict__ beta,
    const float* __restrict__ Wpost, const float* __restrict__ gate, float* out) {
  int p = blockIdx.x * 256 + threadIdx.x;
  int b = blockIdx.y;
  float sg = 1.f / (1.f + __expf(-gate[0]));
  float nv[Cn];
#pragma unroll
  for (int c = 0; c < Cn; ++c) {
    float mu = stat[(b * Cn + c) * 2 + 0];
    float rstd = stat[(b * Cn + c) * 2 + 1];
    float yv = (t[((size_t)b * Cn + c) * DHW + p] - mu) * rstd * gamma[c] + beta[c];
    float u = 0.7978845608028654f * (yv + 0.044715f * yv * yv * yv);
    float e = __expf(2.f * u);
    float th = 1.f - 2.f / (e + 1.f);
    nv[c] = 0.5f * yv * (1.f + th);
  }
#pragma unroll 1
  for (int o = 0; o < Cn; ++o) {
    float s = 0.f;
#pragma unroll
    for (int c = 0; c < Cn; ++c) s += Wpost[o * Cn + c] * nv[c];
    size_t i = ((size_t)b * Cn + o) * DHW + p;
    out[i] = x[i] + sg * s;
  }
}

extern "C" void kernel_launch(void* const* d_in, const int* in_sizes, int n_in,
                              void* d_out, int out_size, void* d_ws, size_t ws_size,
                              hipStream_t stream) {
  const float* x          = (const float*)d_in[0];
  const float* gate       = (const float*)d_in[1];
  const float* pre_w      = (const float*)d_in[2];
  const float* post_w     = (const float*)d_in[3];
  const float* in_proj_w  = (const float*)d_in[4];
  const float* in_proj_b  = (const float*)d_in[5];
  const float* out_proj_w = (const float*)d_in[6];
  const float* out_proj_b = (const float*)d_in[7];
  const float* off_w      = (const float*)d_in[8];
  const float* off_b      = (const float*)d_in[9];
  const float* mask_w     = (const float*)d_in[10];
  const float* mask_b     = (const float*)d_in[11];
  const float* in_gamma   = (const float*)d_in[12];
  const float* in_beta    = (const float*)d_in[13];

  char* ws = (char*)d_ws;
  __hip_bfloat16* xpadh = (__hip_bfloat16*)(ws + XPADH_OFF);
  short8* Wfrag  = (short8*)(ws + WFRAG_OFF);
  float* Wv      = (float*)(ws + WV_OFF);
  __hip_bfloat16* convout = (__hip_bfloat16*)(ws + CONV_OFF);
  float* v       = (float*)(ws + V_OFF);
  __hip_bfloat16* sampled = (__hip_bfloat16*)(ws + SAMP_OFF);
  float* stat    = (float*)(ws + STAT_OFF);
  float* t   = (float*)d_out;
  float* out = (float*)d_out;

  int zf16 = (int)(XPADH_B / 16);
  zerofill<<<(zf16 + 255) / 256, 256, 0, stream>>>((uint4*)xpadh, zf16);
  fillpad<<<dim3(8, 16, 2), 256, 0, stream>>>(x, xpadh);
  int foldN = (64 * 64 + 54 * 16 * 64 + 255) / 256;
  fold_weights<<<foldN, 256, 0, stream>>>(pre_w, in_proj_w, off_w, mask_w, Wfrag, Wv);
  vproj<<<dim3(DHW / 256, Bn), 256, 0, stream>>>(x, Wv, in_proj_b, v);
  conv_mfma<<<dim3(32, 16, 2), 512, 0, stream>>>((const char*)xpadh, (const uint4*)Wfrag,
                                                 off_b, mask_b, convout);
  dcn_sample<<<dim3(DHW / 256, Bn * Gn), 256, 0, stream>>>(convout, v, sampled);
  outproj<<<dim3(DHW / 256, Bn), 256, 0, stream>>>(sampled, out_proj_w, out_proj_b, t);
  stats_k<<<Bn * Cn, 256, 0, stream>>>(t, stat);
  finalk<<<dim3(DHW / 256, Bn), 256, 0, stream>>>(t, x, stat, in_gamma, in_beta,
                                                  post_w, gate, out);
}

// Round 3
// 593.642 us; speedup vs baseline: 3.6997x; 1.9859x over previous
//
#include <hip/hip_runtime.h>
#include <hip/hip_bf16.h>

typedef short short8 __attribute__((ext_vector_type(8)));
typedef float f32x4 __attribute__((ext_vector_type(4)));

namespace {
constexpr int Bn = 2, Cn = 64, Dn = 16, Hn = 64, Wn = 64;
constexpr int Gn = 2, Kn = 27, GCn = 32;
constexpr int DHW = Dn * Hn * Wn;                 // 65536
constexpr int OCn = 216;                          // 162 off + 54 mask
constexpr int PD = 18, PH = 66, PW = 66;
constexpr float EPS = 1e-5f;

// conv patch: 3d x 4h x 66w rows of 128B (64ch bf16)
constexpr int PROWS = 12 * 66;                    // 792
constexpr int PATCH_B = PROWS * 128;              // 101376
constexpr int ABUF_B = 16384;                     // 256 rows x 32 k x 2B

constexpr size_t XPADH_OFF = 0;
constexpr size_t XPADH_B   = (size_t)Bn * PD * PH * PW * Cn * 2;   // 20,072,448
constexpr size_t WFRAG_OFF = XPADH_OFF + XPADH_B;
constexpr size_t WFRAG_B   = (size_t)54 * 16 * 64 * 16;            // 884,736
constexpr size_t WV_OFF    = WFRAG_OFF + WFRAG_B;
constexpr size_t WV_B      = 64 * 64 * 4;
constexpr size_t CONV_OFF  = WV_OFF + WV_B;
constexpr size_t CONV_B    = (size_t)Bn * OCn * DHW * 2;           // 56,623,104
constexpr size_t V_OFF     = CONV_OFF + CONV_B;
constexpr size_t V_B       = (size_t)Bn * Gn * DHW * GCn * 2;      // 16,777,216 (bf16)
constexpr size_t SAMP_OFF  = V_OFF + V_B;
constexpr size_t SAMP_B    = (size_t)Bn * Gn * DHW * GCn * 2;      // 16,777,216
constexpr size_t STAT_OFF  = SAMP_OFF + SAMP_B;
}

__device__ inline float b2f(short s) {
  union { float f; unsigned u; } x; x.u = ((unsigned)(unsigned short)s) << 16; return x.f;
}
__device__ inline short f2b(float f) {
  __hip_bfloat16 h = __float2bfloat16(f);
  union { __hip_bfloat16 h; short s; } x; x.h = h; return x.s;
}
__device__ inline int iclamp(int v, int lo, int hi) { return v < lo ? lo : (v > hi ? hi : v); }

// ---- zero-fill padded input volume ----
__global__ __launch_bounds__(256) void zerofill(uint4* __restrict__ p, int n16) {
  int i = blockIdx.x * 256 + threadIdx.x;
  if (i < n16) p[i] = make_uint4(0, 0, 0, 0);
}

// ---- transpose-pad x [b,c,d,h,w] f32 -> xpadh [b,dz,hy,wx,c] bf16 (interior) ----
__device__ inline int tp_addr(int hh, int w, int c) {
  return (hh * 64 + w) * 128 + (((c >> 3) ^ (w & 7)) << 4) +
         (((((c & 7) >> 1) ^ ((w >> 3) & 3))) << 2) + ((c & 1) << 1);
}
__global__ __launch_bounds__(256) void fillpad(const float* __restrict__ x,
                                               __hip_bfloat16* __restrict__ xpadh) {
  __shared__ char lds[8 * 64 * 128];               // 64KB: 8h x 64w x 64c bf16 (swizzled)
  int tid = threadIdx.x;
  int hc = blockIdx.x, d = blockIdx.y, b = blockIdx.z;
  int h0 = hc * 8;
  {
    int cq = tid >> 6, w = tid & 63;
#pragma unroll 1
    for (int cc = 0; cc < 16; ++cc) {
      int c = cc * 4 + cq;
      const float* xr = x + ((size_t)(b * 64 + c)) * DHW + d * 4096 + w;
#pragma unroll
      for (int hh = 0; hh < 8; ++hh) {
        float v = xr[(h0 + hh) * 64];
        *(short*)(lds + tp_addr(hh, w, c)) = f2b(v);
      }
    }
  }
  __syncthreads();
  {
    int c = tid & 63, w4 = tid >> 6;
    __hip_bfloat16* ob = xpadh + (size_t)b * (PD * PH * PW * 64);
#pragma unroll 1
    for (int hh = 0; hh < 8; ++hh) {
      size_t rowb = (((size_t)(d + 1) * 66) + (h0 + hh + 1)) * 66;
#pragma unroll
      for (int wq = 0; wq < 16; ++wq) {
        int w = wq * 4 + w4;
        short v = *(const short*)(lds + tp_addr(hh, w, c));
        *(short*)(ob + (rowb + w + 1) * 64 + c) = v;
      }
    }
  }
}

// ---- fold pre 1x1 into conv weights (MFMA fragment order) and value projection ----
__global__ __launch_bounds__(256) void fold_weights(
    const float* __restrict__ pre_w, const float* __restrict__ in_proj_w,
    const float* __restrict__ off_w, const float* __restrict__ mask_w,
    short8* __restrict__ Wfrag, float* __restrict__ Wv) {
  int i = blockIdx.x * 256 + threadIdx.x;
  if (i < 64 * 64) {
    int o = i >> 6, c = i & 63;
    float s = 0.f;
    for (int cp = 0; cp < 64; ++cp) s += in_proj_w[o * 64 + cp] * pre_w[cp * 64 + c];
    Wv[i] = s;
    return;
  }
  int t = i - 64 * 64;
  if (t >= 54 * 16 * 64) return;
  int l = t & 63; int rest = t >> 6;
  int mt = rest & 15; int ks = rest >> 4;
  int oc = mt * 16 + (l & 15);
  int tap = ks >> 1;
  int c0 = (ks & 1) * 32 + (l >> 4) * 8;
  float vals[8] = {0.f, 0.f, 0.f, 0.f, 0.f, 0.f, 0.f, 0.f};
  if (oc < OCn) {
    const float* cw = (oc < 162) ? (off_w + (size_t)oc * 64 * 27)
                                 : (mask_w + (size_t)(oc - 162) * 64 * 27);
#pragma unroll 1
    for (int cp = 0; cp < 64; ++cp) {
      float wv = cw[cp * 27 + tap];
      const float* pr = pre_w + cp * 64 + c0;
#pragma unroll
      for (int j = 0; j < 8; ++j) vals[j] += wv * pr[j];
    }
  }
  short8 o8;
#pragma unroll
  for (int j = 0; j < 8; ++j) o8[j] = f2b(vals[j]);
  Wfrag[t] = o8;
}

// ---- value projection v = (in_proj_w @ pre_w) @ x + b, bf16 layout [b,g,p,32] ----
__global__ __launch_bounds__(256) void vproj(
    const float* __restrict__ x, const float* __restrict__ Wv,
    const float* __restrict__ vb, __hip_bfloat16* __restrict__ v) {
  int p = blockIdx.x * 256 + threadIdx.x;
  int b = blockIdx.y;
  const float* xb = x + (size_t)b * Cn * DHW;
  float xv[Cn];
#pragma unroll
  for (int c = 0; c < Cn; ++c) xv[c] = xb[c * DHW + p];
#pragma unroll 1
  for (int g = 0; g < Gn; ++g) {
    float vo[GCn];
#pragma unroll
    for (int j = 0; j < GCn; ++j) {
      int o = g * GCn + j;
      float s = vb[o];
#pragma unroll
      for (int c = 0; c < Cn; ++c) s += Wv[o * Cn + c] * xv[c];
      vo[j] = s;
    }
    short8* dst = (short8*)(v + ((size_t)(b * Gn + g) * DHW + p) * GCn);
#pragma unroll
    for (int q = 0; q < 4; ++q) {
      short8 o8;
#pragma unroll
      for (int j = 0; j < 8; ++j) o8[j] = f2b(vo[q * 8 + j]);
      dst[q] = o8;
    }
  }
}

// ---- MFMA implicit-GEMM 3x3x3 conv: M=256(216) oc x N=128 pos, K=1728 ----
__global__ __launch_bounds__(512, 2) void conv_mfma(
    const char* __restrict__ xpadh, const uint4* __restrict__ wfrag,
    const float* __restrict__ off_b, const float* __restrict__ mask_b,
    __hip_bfloat16* __restrict__ convout) {
  __shared__ char lds[PATCH_B + 2 * ABUF_B];       // 134,144 B
  int tid = threadIdx.x;
  int h0 = blockIdx.x * 2, d = blockIdx.y, b = blockIdx.z;

  const char* xb = xpadh + (size_t)b * (PD * PH * PW * 128);
  for (int idx = tid; idx < PROWS * 8; idx += 512) {
    int s = idx >> 3, slot = idx & 7;
    int r12 = s / 66, wx = s - r12 * 66;
    int dp = r12 >> 2, hp = r12 & 3;
    const char* g = xb + ((((size_t)(d + dp)) * 66 + (h0 + hp)) * 66 + wx) * 128 + slot * 16;
    uint4 vv = *(const uint4*)g;
    *(uint4*)(lds + s * 128 + ((slot ^ (s & 7)) << 4)) = vv;
  }
  for (int u = tid; u < 1024; u += 512)
    *(uint4*)(lds + PATCH_B + u * 16) = wfrag[u];
  __syncthreads();

  int wid = tid >> 6, l = tid & 63;
  int wm = wid & 3, wn = wid >> 2;
  int lm = l & 15, lk = l >> 4;
  f32x4 acc[4][4];
#pragma unroll
  for (int mt = 0; mt < 4; ++mt)
#pragma unroll
    for (int nt = 0; nt < 4; ++nt) acc[mt][nt] = (f32x4){0.f, 0.f, 0.f, 0.f};

#pragma unroll 1
  for (int ks = 0; ks < 54; ++ks) {
    int cur = ks & 1;
    uint4 st0, st1;
    if (ks < 53) {
      st0 = wfrag[(ks + 1) * 1024 + tid];
      st1 = wfrag[(ks + 1) * 1024 + tid + 512];
    }
    int tap = ks >> 1;
    int dd = tap / 9, rem = tap - dd * 9, dh = rem / 3, dw = rem - dh * 3;
    int srow = (dd * 4 + wn + dh) * 66 + dw;
    int uslot = 4 * (ks & 1) + lk;
    short8 bfr[4];
#pragma unroll
    for (int nt = 0; nt < 4; ++nt) {
      int s = srow + nt * 16 + lm;
      bfr[nt] = *(const short8*)(lds + s * 128 + ((uslot ^ (s & 7)) << 4));
    }
    const char* abase = lds + PATCH_B + cur * ABUF_B + (wm * 256 + l) * 16;
    short8 afr[4];
#pragma unroll
    for (int mt = 0; mt < 4; ++mt)
      afr[mt] = *(const short8*)(abase + mt * 1024);
#pragma unroll
    for (int mt = 0; mt < 4; ++mt)
#pragma unroll
      for (int nt = 0; nt < 4; ++nt)
        acc[mt][nt] = __builtin_amdgcn_mfma_f32_16x16x32_bf16(afr[mt], bfr[nt], acc[mt][nt], 0, 0, 0);
    if (ks < 53) {
      char* adst = lds + PATCH_B + (cur ^ 1) * ABUF_B;
      *(uint4*)(adst + tid * 16) = st0;
      *(uint4*)(adst + (tid + 512) * 16) = st1;
    }
    __syncthreads();
  }

  int pbase = d * 4096 + (h0 + wn) * 64;
#pragma unroll
  for (int mt = 0; mt < 4; ++mt) {
    int oc0 = wm * 64 + mt * 16 + lk * 4;
#pragma unroll
    for (int r = 0; r < 4; ++r) {
      int oc = oc0 + r;
      if (oc < OCn) {
        float bias = (oc < 162) ? off_b[oc] : mask_b[oc - 162];
        size_t orow = ((size_t)b * OCn + oc) * DHW + pbase;
#pragma unroll
        for (int nt = 0; nt < 4; ++nt)
          convout[orow + nt * 16 + lm] = __float2bfloat16(acc[mt][nt][r] + bias);
      }
    }
  }
}

// ---- deformable trilinear sampling + fused mask softmax ----
// 2 threads per (p,g): 16 channels each. Offsets/masks LDS-staged per 128-pos block.
__global__ __launch_bounds__(256) void dcn_sample(
    const __hip_bfloat16* __restrict__ convout, const __hip_bfloat16* __restrict__ v,
    __hip_bfloat16* __restrict__ sampled) {
  __shared__ short offm[108 * 128];                // 27,648 B
  int tid = threadIdx.x;
  int bg = blockIdx.y;
  int b = bg >> 1, g = bg & 1;
  int p0 = blockIdx.x * 128;

  const __hip_bfloat16* cb = convout + (size_t)b * OCn * DHW;
#pragma unroll 1
  for (int idx = tid; idx < 108 * 16; idx += 256) {
    int row = idx >> 4, col = idx & 15;
    int oc = (row < 81) ? (g * 81 + row) : (162 + g * Kn + (row - 81));
    uint4 vv = *(const uint4*)(cb + (size_t)oc * DHW + p0 + col * 8);
    *(uint4*)(offm + row * 128 + col * 8) = vv;
  }
  __syncthreads();

  int pl = tid >> 1, half = tid & 1;
  int p = p0 + pl;
  int w = p & 63, h = (p >> 6) & 63, d = p >> 12;

  float mx = -1e30f;
#pragma unroll 1
  for (int k = 0; k < Kn; ++k) mx = fmaxf(mx, b2f(offm[(81 + k) * 128 + pl]));
  float msum = 0.f;
#pragma unroll 1
  for (int k = 0; k < Kn; ++k) msum += __expf(b2f(offm[(81 + k) * 128 + pl]) - mx);
  float rs = 1.f / msum;

  float acc[16];
#pragma unroll
  for (int q = 0; q < 16; ++q) acc[q] = 0.f;
  const __hip_bfloat16* vg = v + (size_t)bg * DHW * GCn + half * 16;

#pragma unroll 1
  for (int k = 0; k < Kn; ++k) {
    float offd = b2f(offm[(3 * k + 0) * 128 + pl]);
    float offh = b2f(offm[(3 * k + 1) * 128 + pl]);
    float offw = b2f(offm[(3 * k + 2) * 128 + pl]);
    float pd = (float)(d + (k / 9) - 1) + offd * 0.5f;
    float ph = (float)(h + ((k / 3) % 3) - 1) + offh;
    float pw = (float)(w + (k % 3) - 1) + offw;
    float fd = floorf(pd), fh = floorf(ph), fw = floorf(pw);
    float td = pd - fd, th = ph - fh, tw = pw - fw;
    int d0 = (int)fd, h0 = (int)fh, w0 = (int)fw;
    float mk = __expf(b2f(offm[(81 + k) * 128 + pl]) - mx) * rs;

#pragma unroll
    for (int dd = 0; dd < 2; ++dd) {
      int di = d0 + dd;
      float wd = (dd ? td : 1.f - td) * mk;
      int dc = iclamp(di, 0, Dn - 1);
      bool vd = (di >= 0) & (di < Dn);
#pragma unroll
      for (int hh = 0; hh < 2; ++hh) {
        int hi = h0 + hh;
        float whf = (hh ? th : 1.f - th) * wd;
        int hc = iclamp(hi, 0, Hn - 1);
        bool vh = (hi >= 0) & (hi < Hn);
#pragma unroll
        for (int ww = 0; ww < 2; ++ww) {
          int wi = w0 + ww;
          float wt = (ww ? tw : 1.f - tw) * whf;
          int wc = iclamp(wi, 0, Wn - 1);
          bool vw = (wi >= 0) & (wi < Wn);
          wt = (vd & vh & vw) ? wt : 0.f;
          int idx = (dc * Hn + hc) * Wn + wc;
          const uint4* src = (const uint4*)(vg + (size_t)idx * GCn);
          uint4 ua = src[0], ub = src[1];
#pragma unroll
          for (int q = 0; q < 4; ++q) {
            unsigned u = (q == 0) ? ua.x : (q == 1) ? ua.y : (q == 2) ? ua.z : ua.w;
            float lo = __uint_as_float(u << 16);
            float hi2 = __uint_as_float(u & 0xffff0000u);
            acc[2 * q] += wt * lo; acc[2 * q + 1] += wt * hi2;
          }
#pragma unroll
          for (int q = 0; q < 4; ++q) {
            unsigned u = (q == 0) ? ub.x : (q == 1) ? ub.y : (q == 2) ? ub.z : ub.w;
            float lo = __uint_as_float(u << 16);
            float hi2 = __uint_as_float(u & 0xffff0000u);
            acc[8 + 2 * q] += wt * lo; acc[8 + 2 * q + 1] += wt * hi2;
          }
        }
      }
    }
  }

  short8* dst = (short8*)(sampled + ((size_t)bg * DHW + p) * GCn + half * 16);
#pragma unroll
  for (int q = 0; q < 2; ++q) {
    short8 o8;
#pragma unroll
    for (int j = 0; j < 8; ++j) o8[j] = f2b(acc[q * 8 + j]);
    dst[q] = o8;
  }
}

// ---- out_proj (t lives in d_out as scratch) ----
__global__ __launch_bounds__(256) void outproj(
    const __hip_bfloat16* __restrict__ sampled, const float* __restrict__ Wout,
    const float* __restrict__ ob, float* __restrict__ t) {
  int p = blockIdx.x * 256 + threadIdx.x;
  int b = blockIdx.y;
  float sv[Cn];
#pragma unroll
  for (int g = 0; g < Gn; ++g) {
    const short8* src = (const short8*)(sampled) + ((size_t)(b * Gn + g) * DHW + p) * 4;
#pragma unroll
    for (int q = 0; q < 4; ++q) {
      short8 s8 = src[q];
#pragma unroll
      for (int j = 0; j < 8; ++j) sv[g * GCn + q * 8 + j] = b2f(s8[j]);
    }
  }
#pragma unroll 1
  for (int o = 0; o < Cn; ++o) {
    float s = ob[o];
#pragma unroll
    for (int c = 0; c < Cn; ++c) s += Wout[o * Cn + c] * sv[c];
    t[((size_t)b * Cn + o) * DHW + p] = s;
  }
}

// ---- per-(b,c) instance-norm stats ----
__global__ __launch_bounds__(256) void stats_k(const float* __restrict__ t,
                                               float* __restrict__ stat) {
  int bc = blockIdx.x;
  const float* tc = t + (size_t)bc * DHW;
  float s = 0.f, ss = 0.f;
  for (int i = threadIdx.x; i < DHW; i += 256) {
    float xv = tc[i]; s += xv; ss += xv * xv;
  }
#pragma unroll
  for (int o = 32; o > 0; o >>= 1) { s += __shfl_down(s, o); ss += __shfl_down(ss, o); }
  __shared__ float ls[4], lss[4];
  int wid = threadIdx.x >> 6;
  if ((threadIdx.x & 63) == 0) { ls[wid] = s; lss[wid] = ss; }
  __syncthreads();
  if (threadIdx.x == 0) {
    float S = ls[0] + ls[1] + ls[2] + ls[3];
    float SS = lss[0] + lss[1] + lss[2] + lss[3];
    float mu = S / (float)DHW;
    float var = SS / (float)DHW - mu * mu;
    stat[bc * 2 + 0] = mu;
    stat[bc * 2 + 1] = rsqrtf(var + EPS);
  }
}

// ---- norm + gelu + post 1x1 + gated residual ----
__global__ __launch_bounds__(256) void finalk(
    const float* t, const float* __restrict__ x, const float* __restrict__ stat,
    const float* __restrict__ gamma, const float* __restrict__ beta,
    const float* __restrict__ Wpost, const float* __restrict__ gate, float* out) {
  int p = blockIdx.x * 256 + threadIdx.x;
  int b = blockIdx.y;
  float sg = 1.f / (1.f + __expf(-gate[0]));
  float nv[Cn];
#pragma unroll
  for (int c = 0; c < Cn; ++c) {
    float mu = stat[(b * Cn + c) * 2 + 0];
    float rstd = stat[(b * Cn + c) * 2 + 1];
    float yv = (t[((size_t)b * Cn + c) * DHW + p] - mu) * rstd * gamma[c] + beta[c];
    float u = 0.7978845608028654f * (yv + 0.044715f * yv * yv * yv);
    float e = __expf(2.f * u);
    float th = 1.f - 2.f / (e + 1.f);
    nv[c] = 0.5f * yv * (1.f + th);
  }
#pragma unroll 1
  for (int o = 0; o < Cn; ++o) {
    float s = 0.f;
#pragma unroll
    for (int c = 0; c < Cn; ++c) s += Wpost[o * Cn + c] * nv[c];
    size_t i = ((size_t)b * Cn + o) * DHW + p;
    out[i] = x[i] + sg * s;
  }
}

extern "C" void kernel_launch(void* const* d_in, const int* in_sizes, int n_in,
                              void* d_out, int out_size, void* d_ws, size_t ws_size,
                              hipStream_t stream) {
  const float* x          = (const float*)d_in[0];
  const float* gate       = (const float*)d_in[1];
  const float* pre_w      = (const float*)d_in[2];
  const float* post_w     = (const float*)d_in[3];
  const float* in_proj_w  = (const float*)d_in[4];
  const float* in_proj_b  = (const float*)d_in[5];
  const float* out_proj_w = (const float*)d_in[6];
  const float* out_proj_b = (const float*)d_in[7];
  const float* off_w      = (const float*)d_in[8];
  const float* off_b      = (const float*)d_in[9];
  const float* mask_w     = (const float*)d_in[10];
  const float* mask_b     = (const float*)d_in[11];
  const float* in_gamma   = (const float*)d_in[12];
  const float* in_beta    = (const float*)d_in[13];

  char* ws = (char*)d_ws;
  __hip_bfloat16* xpadh = (__hip_bfloat16*)(ws + XPADH_OFF);
  short8* Wfrag  = (short8*)(ws + WFRAG_OFF);
  float* Wv      = (float*)(ws + WV_OFF);
  __hip_bfloat16* convout = (__hip_bfloat16*)(ws + CONV_OFF);
  __hip_bfloat16* v       = (__hip_bfloat16*)(ws + V_OFF);
  __hip_bfloat16* sampled = (__hip_bfloat16*)(ws + SAMP_OFF);
  float* stat    = (float*)(ws + STAT_OFF);
  float* t   = (float*)d_out;
  float* out = (float*)d_out;

  int zf16 = (int)(XPADH_B / 16);
  zerofill<<<(zf16 + 255) / 256, 256, 0, stream>>>((uint4*)xpadh, zf16);
  fillpad<<<dim3(8, 16, 2), 256, 0, stream>>>(x, xpadh);
  int foldN = (64 * 64 + 54 * 16 * 64 + 255) / 256;
  fold_weights<<<foldN, 256, 0, stream>>>(pre_w, in_proj_w, off_w, mask_w, Wfrag, Wv);
  vproj<<<dim3(DHW / 256, Bn), 256, 0, stream>>>(x, Wv, in_proj_b, v);
  conv_mfma<<<dim3(32, 16, 2), 512, 0, stream>>>((const char*)xpadh, (const uint4*)Wfrag,
                                                 off_b, mask_b, convout);
  dcn_sample<<<dim3(DHW / 128, Bn * Gn), 256, 0, stream>>>(convout, v, sampled);
  outproj<<<dim3(DHW / 256, Bn), 256, 0, stream>>>(sampled, out_proj_w, out_proj_b, t);
  stats_k<<<Bn * Cn, 256, 0, stream>>>(t, stat);
  finalk<<<dim3(DHW / 256, Bn), 256, 0, stream>>>(t, x, stat, in_gamma, in_beta,
                                                  post_w, gate, out);
}

// Round 4
// 540.858 us; speedup vs baseline: 4.0608x; 1.0976x over previous
//
#include <hip/hip_runtime.h>
#include <hip/hip_bf16.h>

typedef short short8 __attribute__((ext_vector_type(8)));
typedef float f32x4 __attribute__((ext_vector_type(4)));
typedef float f32x2 __attribute__((ext_vector_type(2)));

#if __has_builtin(__builtin_elementwise_fma)
#define FMA2(a, b, c) __builtin_elementwise_fma((a), (b), (c))
#else
#define FMA2(a, b, c) ((a) * (b) + (c))
#endif

namespace {
constexpr int Bn = 2, Cn = 64, Dn = 16, Hn = 64, Wn = 64;
constexpr int Gn = 2, Kn = 27, GCn = 32;
constexpr int DHW = Dn * Hn * Wn;                 // 65536
constexpr int OCn = 216;                          // 162 off + 54 mask
constexpr int PD = 18, PH = 66, PW = 66;
constexpr float EPS = 1e-5f;

// conv patch: 3d x 4h x 66w rows of 128B (64ch bf16)
constexpr int PROWS = 12 * 66;                    // 792
constexpr int PATCH_B = PROWS * 128;              // 101376
constexpr int ABUF_B = 16384;                     // 256 rows x 32 k x 2B

constexpr size_t XPADH_OFF = 0;
constexpr size_t XPADH_B   = (size_t)Bn * PD * PH * PW * Cn * 2;   // 20,072,448
constexpr size_t WFRAG_OFF = XPADH_OFF + XPADH_B;
constexpr size_t WFRAG_B   = (size_t)54 * 16 * 64 * 16;            // 884,736
constexpr size_t WV_OFF    = WFRAG_OFF + WFRAG_B;
constexpr size_t WV_B      = 64 * 64 * 4;
constexpr size_t CONV_OFF  = WV_OFF + WV_B;
constexpr size_t CONV_B    = (size_t)Bn * OCn * DHW * 2;           // 56,623,104
constexpr size_t V_OFF     = CONV_OFF + CONV_B;
constexpr size_t V_B       = (size_t)Bn * Gn * DHW * GCn * 2;      // 16,777,216 (bf16)
constexpr size_t SAMP_OFF  = V_OFF + V_B;
constexpr size_t SAMP_B    = (size_t)Bn * Gn * DHW * GCn * 2;      // 16,777,216
constexpr size_t STAT_OFF  = SAMP_OFF + SAMP_B;
// t (bf16, 16.7MB) reuses the xpadh region (dead after conv_mfma)
}

__device__ inline float b2f(short s) {
  union { float f; unsigned u; } x; x.u = ((unsigned)(unsigned short)s) << 16; return x.f;
}
__device__ inline short f2b(float f) {
  __hip_bfloat16 h = __float2bfloat16(f);
  union { __hip_bfloat16 h; short s; } x; x.h = h; return x.s;
}
__device__ inline int iclamp(int v, int lo, int hi) { return v < lo ? lo : (v > hi ? hi : v); }
__device__ inline f32x2 up2(unsigned u) {
  f32x2 r; r.x = __uint_as_float(u << 16); r.y = __uint_as_float(u & 0xffff0000u); return r;
}

// ---- zero-fill padded input volume ----
__global__ __launch_bounds__(256) void zerofill(uint4* __restrict__ p, int n16) {
  int i = blockIdx.x * 256 + threadIdx.x;
  if (i < n16) p[i] = make_uint4(0, 0, 0, 0);
}

// ---- transpose-pad x [b,c,d,h,w] f32 -> xpadh [b,dz,hy,wx,c] bf16 (interior) ----
__device__ inline int tp_addr(int hh, int w, int c) {
  return (hh * 64 + w) * 128 + (((c >> 3) ^ (w & 7)) << 4) +
         (((((c & 7) >> 1) ^ ((w >> 3) & 3))) << 2) + ((c & 1) << 1);
}
__global__ __launch_bounds__(256) void fillpad(const float* __restrict__ x,
                                               __hip_bfloat16* __restrict__ xpadh) {
  __shared__ char lds[8 * 64 * 128];               // 64KB
  int tid = threadIdx.x;
  int hc = blockIdx.x, d = blockIdx.y, b = blockIdx.z;
  int h0 = hc * 8;
  {
    int cq = tid >> 6, w = tid & 63;
#pragma unroll 1
    for (int cc = 0; cc < 16; ++cc) {
      int c = cc * 4 + cq;
      const float* xr = x + ((size_t)(b * 64 + c)) * DHW + d * 4096 + w;
#pragma unroll
      for (int hh = 0; hh < 8; ++hh) {
        float v = xr[(h0 + hh) * 64];
        *(short*)(lds + tp_addr(hh, w, c)) = f2b(v);
      }
    }
  }
  __syncthreads();
  {
    int c = tid & 63, w4 = tid >> 6;
    __hip_bfloat16* ob = xpadh + (size_t)b * (PD * PH * PW * 64);
#pragma unroll 1
    for (int hh = 0; hh < 8; ++hh) {
      size_t rowb = (((size_t)(d + 1) * 66) + (h0 + hh + 1)) * 66;
#pragma unroll
      for (int wq = 0; wq < 16; ++wq) {
        int w = wq * 4 + w4;
        short v = *(const short*)(lds + tp_addr(hh, w, c));
        *(short*)(ob + (rowb + w + 1) * 64 + c) = v;
      }
    }
  }
}

// ---- fold pre 1x1 into conv weights (MFMA fragment order) and value projection ----
__global__ __launch_bounds__(256) void fold_weights(
    const float* __restrict__ pre_w, const float* __restrict__ in_proj_w,
    const float* __restrict__ off_w, const float* __restrict__ mask_w,
    short8* __restrict__ Wfrag, float* __restrict__ Wv) {
  int i = blockIdx.x * 256 + threadIdx.x;
  if (i < 64 * 64) {
    int o = i >> 6, c = i & 63;
    float s = 0.f;
    for (int cp = 0; cp < 64; ++cp) s += in_proj_w[o * 64 + cp] * pre_w[cp * 64 + c];
    Wv[i] = s;
    return;
  }
  int t = i - 64 * 64;
  if (t >= 54 * 16 * 64) return;
  int l = t & 63; int rest = t >> 6;
  int mt = rest & 15; int ks = rest >> 4;
  int oc = mt * 16 + (l & 15);
  int tap = ks >> 1;
  int c0 = (ks & 1) * 32 + (l >> 4) * 8;
  float vals[8] = {0.f, 0.f, 0.f, 0.f, 0.f, 0.f, 0.f, 0.f};
  if (oc < OCn) {
    const float* cw = (oc < 162) ? (off_w + (size_t)oc * 64 * 27)
                                 : (mask_w + (size_t)(oc - 162) * 64 * 27);
#pragma unroll 1
    for (int cp = 0; cp < 64; ++cp) {
      float wv = cw[cp * 27 + tap];
      const float* pr = pre_w + cp * 64 + c0;
#pragma unroll
      for (int j = 0; j < 8; ++j) vals[j] += wv * pr[j];
    }
  }
  short8 o8;
#pragma unroll
  for (int j = 0; j < 8; ++j) o8[j] = f2b(vals[j]);
  Wfrag[t] = o8;
}

// ---- value projection v = (in_proj_w @ pre_w) @ x + b, bf16 layout [b,g,p,32] ----
__global__ __launch_bounds__(256) void vproj(
    const float* __restrict__ x, const float* __restrict__ Wv,
    const float* __restrict__ vb, __hip_bfloat16* __restrict__ v) {
  int p = blockIdx.x * 256 + threadIdx.x;
  int b = blockIdx.y;
  const float* xb = x + (size_t)b * Cn * DHW;
  float xv[Cn];
#pragma unroll
  for (int c = 0; c < Cn; ++c) xv[c] = xb[c * DHW + p];
#pragma unroll 1
  for (int g = 0; g < Gn; ++g) {
    float vo[GCn];
#pragma unroll
    for (int j = 0; j < GCn; ++j) {
      int o = g * GCn + j;
      float s = vb[o];
#pragma unroll
      for (int c = 0; c < Cn; ++c) s += Wv[o * Cn + c] * xv[c];
      vo[j] = s;
    }
    short8* dst = (short8*)(v + ((size_t)(b * Gn + g) * DHW + p) * GCn);
#pragma unroll
    for (int q = 0; q < 4; ++q) {
      short8 o8;
#pragma unroll
      for (int j = 0; j < 8; ++j) o8[j] = f2b(vo[q * 8 + j]);
      dst[q] = o8;
    }
  }
}

// ---- MFMA implicit-GEMM 3x3x3 conv: M=256(216) oc x N=128 pos, K=1728 ----
// 1024 threads = 16 waves (4/SIMD): wave = (wm oc-quarter) x (wn 32-pos quarter)
__global__ __launch_bounds__(1024, 1) void conv_mfma(
    const char* __restrict__ xpadh, const uint4* __restrict__ wfrag,
    const float* __restrict__ off_b, const float* __restrict__ mask_b,
    __hip_bfloat16* __restrict__ convout) {
  __shared__ char lds[PATCH_B + 2 * ABUF_B];       // 134,144 B -> 1 block/CU
  int tid = threadIdx.x;
  int h0 = blockIdx.x * 2, d = blockIdx.y, b = blockIdx.z;

  const char* xb = xpadh + (size_t)b * (PD * PH * PW * 128);
  for (int idx = tid; idx < PROWS * 8; idx += 1024) {
    int s = idx >> 3, slot = idx & 7;
    int r12 = s / 66, wx = s - r12 * 66;
    int dp = r12 >> 2, hp = r12 & 3;
    const char* g = xb + ((((size_t)(d + dp)) * 66 + (h0 + hp)) * 66 + wx) * 128 + slot * 16;
    uint4 vv = *(const uint4*)g;
    *(uint4*)(lds + s * 128 + ((slot ^ (s & 7)) << 4)) = vv;
  }
  *(uint4*)(lds + PATCH_B + tid * 16) = wfrag[tid];
  __syncthreads();

  int wid = tid >> 6, l = tid & 63;
  int wm = wid & 3, wn = wid >> 2;                 // wm: oc quarter; wn: 0..3
  int hrow = wn >> 1, wq = wn & 1;                 // h row, w half
  int lm = l & 15, lk = l >> 4;
  f32x4 acc[4][2];
#pragma unroll
  for (int mt = 0; mt < 4; ++mt)
#pragma unroll
    for (int nt = 0; nt < 2; ++nt) acc[mt][nt] = (f32x4){0.f, 0.f, 0.f, 0.f};

#pragma unroll 1
  for (int ks = 0; ks < 54; ++ks) {
    int cur = ks & 1;
    uint4 st0;
    if (ks < 53) st0 = wfrag[(ks + 1) * 1024 + tid];
    int tap = ks >> 1;
    int dd = tap / 9, rem = tap - dd * 9, dh = rem / 3, dw = rem - dh * 3;
    int srow = (dd * 4 + hrow + dh) * 66 + dw;
    int uslot = 4 * (ks & 1) + lk;
    short8 bfr[2];
#pragma unroll
    for (int nt = 0; nt < 2; ++nt) {
      int s = srow + wq * 32 + nt * 16 + lm;
      bfr[nt] = *(const short8*)(lds + s * 128 + ((uslot ^ (s & 7)) << 4));
    }
    const char* abase = lds + PATCH_B + cur * ABUF_B + (wm * 256 + l) * 16;
    short8 afr[4];
#pragma unroll
    for (int mt = 0; mt < 4; ++mt)
      afr[mt] = *(const short8*)(abase + mt * 1024);
#pragma unroll
    for (int mt = 0; mt < 4; ++mt)
#pragma unroll
      for (int nt = 0; nt < 2; ++nt)
        acc[mt][nt] = __builtin_amdgcn_mfma_f32_16x16x32_bf16(afr[mt], bfr[nt], acc[mt][nt], 0, 0, 0);
    if (ks < 53)
      *(uint4*)(lds + PATCH_B + (cur ^ 1) * ABUF_B + tid * 16) = st0;
    __syncthreads();
  }

  int pbase = d * 4096 + (h0 + hrow) * 64 + wq * 32;
#pragma unroll
  for (int mt = 0; mt < 4; ++mt) {
    int oc0 = wm * 64 + mt * 16 + lk * 4;
#pragma unroll
    for (int r = 0; r < 4; ++r) {
      int oc = oc0 + r;
      if (oc < OCn) {
        float bias = (oc < 162) ? off_b[oc] : mask_b[oc - 162];
        size_t orow = ((size_t)b * OCn + oc) * DHW + pbase;
#pragma unroll
        for (int nt = 0; nt < 2; ++nt)
          convout[orow + nt * 16 + lm] = __float2bfloat16(acc[mt][nt][r] + bias);
      }
    }
  }
}

// ---- deformable trilinear sampling + fused mask softmax (pk_fma accumulation) ----
__global__ __launch_bounds__(256) void dcn_sample(
    const __hip_bfloat16* __restrict__ convout, const __hip_bfloat16* __restrict__ v,
    __hip_bfloat16* __restrict__ sampled) {
  __shared__ short offm[108 * 128];                // 27,648 B
  int tid = threadIdx.x;
  int bg = blockIdx.y;
  int b = bg >> 1, g = bg & 1;
  int p0 = blockIdx.x * 128;

  const __hip_bfloat16* cb = convout + (size_t)b * OCn * DHW;
#pragma unroll 1
  for (int idx = tid; idx < 108 * 16; idx += 256) {
    int row = idx >> 4, col = idx & 15;
    int oc = (row < 81) ? (g * 81 + row) : (162 + g * Kn + (row - 81));
    uint4 vv = *(const uint4*)(cb + (size_t)oc * DHW + p0 + col * 8);
    *(uint4*)(offm + row * 128 + col * 8) = vv;
  }
  __syncthreads();

  int pl = tid >> 1, half = tid & 1;
  int p = p0 + pl;
  int w = p & 63, h = (p >> 6) & 63, d = p >> 12;

  float mx = -1e30f;
#pragma unroll 1
  for (int k = 0; k < Kn; ++k) mx = fmaxf(mx, b2f(offm[(81 + k) * 128 + pl]));
  float msum = 0.f;
#pragma unroll 1
  for (int k = 0; k < Kn; ++k) msum += __expf(b2f(offm[(81 + k) * 128 + pl]) - mx);
  float rs = 1.f / msum;

  f32x2 acc[8];
#pragma unroll
  for (int q = 0; q < 8; ++q) acc[q] = (f32x2){0.f, 0.f};
  const char* vg = (const char*)v + ((size_t)bg * DHW * GCn + half * 16) * 2;

#pragma unroll 1
  for (int k = 0; k < Kn; ++k) {
    float offd = b2f(offm[(3 * k + 0) * 128 + pl]);
    float offh = b2f(offm[(3 * k + 1) * 128 + pl]);
    float offw = b2f(offm[(3 * k + 2) * 128 + pl]);
    float pd = (float)(d + (k / 9) - 1) + offd * 0.5f;
    float ph = (float)(h + ((k / 3) % 3) - 1) + offh;
    float pw = (float)(w + (k % 3) - 1) + offw;
    float fd = floorf(pd), fh = floorf(ph), fw = floorf(pw);
    float td = pd - fd, th = ph - fh, tw = pw - fw;
    int d0 = (int)fd, h0 = (int)fh, w0 = (int)fw;
    float mk = __expf(b2f(offm[(81 + k) * 128 + pl]) - mx) * rs;

    // per-axis weights with validity folded; mk folded into d-axis
    float wd0 = ((unsigned)d0 < (unsigned)Dn) ? (1.f - td) * mk : 0.f;
    float wd1 = ((unsigned)(d0 + 1) < (unsigned)Dn) ? td * mk : 0.f;
    float wh0 = ((unsigned)h0 < (unsigned)Hn) ? (1.f - th) : 0.f;
    float wh1 = ((unsigned)(h0 + 1) < (unsigned)Hn) ? th : 0.f;
    float ww0 = ((unsigned)w0 < (unsigned)Wn) ? (1.f - tw) : 0.f;
    float ww1 = ((unsigned)(w0 + 1) < (unsigned)Wn) ? tw : 0.f;
    int dr0 = iclamp(d0, 0, Dn - 1) * 4096, dr1 = iclamp(d0 + 1, 0, Dn - 1) * 4096;
    int hr0 = iclamp(h0, 0, Hn - 1) * 64,   hr1 = iclamp(h0 + 1, 0, Hn - 1) * 64;
    int wc0 = iclamp(w0, 0, Wn - 1),        wc1 = iclamp(w0 + 1, 0, Wn - 1);
    float wdh00 = wd0 * wh0, wdh01 = wd0 * wh1, wdh10 = wd1 * wh0, wdh11 = wd1 * wh1;

#define CORNER(RD, RH, WC, WT)                                          \
    {                                                                   \
      float wt_ = (WT);                                                 \
      f32x2 w2_ = {wt_, wt_};                                           \
      const uint4* s_ = (const uint4*)(vg + (size_t)((RD) + (RH) + (WC)) * 64); \
      uint4 ua_ = s_[0], ub_ = s_[1];                                   \
      acc[0] = FMA2(up2(ua_.x), w2_, acc[0]);                           \
      acc[1] = FMA2(up2(ua_.y), w2_, acc[1]);                           \
      acc[2] = FMA2(up2(ua_.z), w2_, acc[2]);                           \
      acc[3] = FMA2(up2(ua_.w), w2_, acc[3]);                           \
      acc[4] = FMA2(up2(ub_.x), w2_, acc[4]);                           \
      acc[5] = FMA2(up2(ub_.y), w2_, acc[5]);                           \
      acc[6] = FMA2(up2(ub_.z), w2_, acc[6]);                           \
      acc[7] = FMA2(up2(ub_.w), w2_, acc[7]);                           \
    }
    CORNER(dr0, hr0, wc0, wdh00 * ww0)
    CORNER(dr0, hr0, wc1, wdh00 * ww1)
    CORNER(dr0, hr1, wc0, wdh01 * ww0)
    CORNER(dr0, hr1, wc1, wdh01 * ww1)
    CORNER(dr1, hr0, wc0, wdh10 * ww0)
    CORNER(dr1, hr0, wc1, wdh10 * ww1)
    CORNER(dr1, hr1, wc0, wdh11 * ww0)
    CORNER(dr1, hr1, wc1, wdh11 * ww1)
#undef CORNER
  }

  const float* af = (const float*)acc;
  short8* dst = (short8*)(sampled + ((size_t)bg * DHW + p) * GCn + half * 16);
#pragma unroll
  for (int q = 0; q < 2; ++q) {
    short8 o8;
#pragma unroll
    for (int j = 0; j < 8; ++j) o8[j] = f2b(af[q * 8 + j]);
    dst[q] = o8;
  }
}

// ---- out_proj: t (bf16, in ws) ----
__global__ __launch_bounds__(256) void outproj(
    const __hip_bfloat16* __restrict__ sampled, const float* __restrict__ Wout,
    const float* __restrict__ ob, __hip_bfloat16* __restrict__ t) {
  int p = blockIdx.x * 256 + threadIdx.x;
  int b = blockIdx.y;
  float sv[Cn];
#pragma unroll
  for (int g = 0; g < Gn; ++g) {
    const short8* src = (const short8*)(sampled) + ((size_t)(b * Gn + g) * DHW + p) * 4;
#pragma unroll
    for (int q = 0; q < 4; ++q) {
      short8 s8 = src[q];
#pragma unroll
      for (int j = 0; j < 8; ++j) sv[g * GCn + q * 8 + j] = b2f(s8[j]);
    }
  }
#pragma unroll 1
  for (int o = 0; o < Cn; ++o) {
    float s = ob[o];
#pragma unroll
    for (int c = 0; c < Cn; ++c) s += Wout[o * Cn + c] * sv[c];
    t[((size_t)b * Cn + o) * DHW + p] = __float2bfloat16(s);
  }
}

// ---- per-(b,c) instance-norm stats (bf16 input, vectorized) ----
__global__ __launch_bounds__(256) void stats_k(const __hip_bfloat16* __restrict__ t,
                                               float* __restrict__ stat) {
  int bc = blockIdx.x;
  const short8* tc = (const short8*)(t + (size_t)bc * DHW);
  float s = 0.f, ss = 0.f;
  for (int i = threadIdx.x; i < DHW / 8; i += 256) {
    short8 s8 = tc[i];
#pragma unroll
    for (int j = 0; j < 8; ++j) { float xv = b2f(s8[j]); s += xv; ss += xv * xv; }
  }
#pragma unroll
  for (int o = 32; o > 0; o >>= 1) { s += __shfl_down(s, o); ss += __shfl_down(ss, o); }
  __shared__ float ls[4], lss[4];
  int wid = threadIdx.x >> 6;
  if ((threadIdx.x & 63) == 0) { ls[wid] = s; lss[wid] = ss; }
  __syncthreads();
  if (threadIdx.x == 0) {
    float S = ls[0] + ls[1] + ls[2] + ls[3];
    float SS = lss[0] + lss[1] + lss[2] + lss[3];
    float mu = S / (float)DHW;
    float var = SS / (float)DHW - mu * mu;
    stat[bc * 2 + 0] = mu;
    stat[bc * 2 + 1] = rsqrtf(var + EPS);
  }
}

// ---- norm + gelu + post 1x1 + gated residual ----
__global__ __launch_bounds__(256) void finalk(
    const __hip_bfloat16* __restrict__ t, const float* __restrict__ x,
    const float* __restrict__ stat,
    const float* __restrict__ gamma, const float* __restrict__ beta,
    const float* __restrict__ Wpost, const float* __restrict__ gate, float* out) {
  int p = blockIdx.x * 256 + threadIdx.x;
  int b = blockIdx.y;
  float sg = 1.f / (1.f + __expf(-gate[0]));
  float nv[Cn];
#pragma unroll
  for (int c = 0; c < Cn; ++c) {
    float mu = stat[(b * Cn + c) * 2 + 0];
    float rstd = stat[(b * Cn + c) * 2 + 1];
    float tv = b2f(((const short*)t)[((size_t)b * Cn + c) * DHW + p]);
    float yv = (tv - mu) * rstd * gamma[c] + beta[c];
    float u = 0.7978845608028654f * (yv + 0.044715f * yv * yv * yv);
    float e = __expf(2.f * u);
    float th = 1.f - 2.f / (e + 1.f);
    nv[c] = 0.5f * yv * (1.f + th);
  }
#pragma unroll 1
  for (int o = 0; o < Cn; ++o) {
    float s = 0.f;
#pragma unroll
    for (int c = 0; c < Cn; ++c) s += Wpost[o * Cn + c] * nv[c];
    size_t i = ((size_t)b * Cn + o) * DHW + p;
    out[i] = x[i] + sg * s;
  }
}

extern "C" void kernel_launch(void* const* d_in, const int* in_sizes, int n_in,
                              void* d_out, int out_size, void* d_ws, size_t ws_size,
                              hipStream_t stream) {
  const float* x          = (const float*)d_in[0];
  const float* gate       = (const float*)d_in[1];
  const float* pre_w      = (const float*)d_in[2];
  const float* post_w     = (const float*)d_in[3];
  const float* in_proj_w  = (const float*)d_in[4];
  const float* in_proj_b  = (const float*)d_in[5];
  const float* out_proj_w = (const float*)d_in[6];
  const float* out_proj_b = (const float*)d_in[7];
  const float* off_w      = (const float*)d_in[8];
  const float* off_b      = (const float*)d_in[9];
  const float* mask_w     = (const float*)d_in[10];
  const float* mask_b     = (const float*)d_in[11];
  const float* in_gamma   = (const float*)d_in[12];
  const float* in_beta    = (const float*)d_in[13];

  char* ws = (char*)d_ws;
  __hip_bfloat16* xpadh = (__hip_bfloat16*)(ws + XPADH_OFF);
  short8* Wfrag  = (short8*)(ws + WFRAG_OFF);
  float* Wv      = (float*)(ws + WV_OFF);
  __hip_bfloat16* convout = (__hip_bfloat16*)(ws + CONV_OFF);
  __hip_bfloat16* v       = (__hip_bfloat16*)(ws + V_OFF);
  __hip_bfloat16* sampled = (__hip_bfloat16*)(ws + SAMP_OFF);
  float* stat    = (float*)(ws + STAT_OFF);
  __hip_bfloat16* t = (__hip_bfloat16*)(ws + XPADH_OFF);   // reuses xpadh region
  float* out = (float*)d_out;

  int zf16 = (int)(XPADH_B / 16);
  zerofill<<<(zf16 + 255) / 256, 256, 0, stream>>>((uint4*)xpadh, zf16);
  fillpad<<<dim3(8, 16, 2), 256, 0, stream>>>(x, xpadh);
  int foldN = (64 * 64 + 54 * 16 * 64 + 255) / 256;
  fold_weights<<<foldN, 256, 0, stream>>>(pre_w, in_proj_w, off_w, mask_w, Wfrag, Wv);
  vproj<<<dim3(DHW / 256, Bn), 256, 0, stream>>>(x, Wv, in_proj_b, v);
  conv_mfma<<<dim3(32, 16, 2), 1024, 0, stream>>>((const char*)xpadh, (const uint4*)Wfrag,
                                                  off_b, mask_b, convout);
  dcn_sample<<<dim3(DHW / 128, Bn * Gn), 256, 0, stream>>>(convout, v, sampled);
  outproj<<<dim3(DHW / 256, Bn), 256, 0, stream>>>(sampled, out_proj_w, out_proj_b, t);
  stats_k<<<Bn * Cn, 256, 0, stream>>>(t, stat);
  finalk<<<dim3(DHW / 256, Bn), 256, 0, stream>>>(t, x, stat, in_gamma, in_beta,
                                                  post_w, gate, out);
}

// Round 5
// 524.360 us; speedup vs baseline: 4.1885x; 1.0315x over previous
//
#include <hip/hip_runtime.h>
#include <hip/hip_bf16.h>

typedef short short8 __attribute__((ext_vector_type(8)));
typedef float f32x4 __attribute__((ext_vector_type(4)));
typedef float f32x2 __attribute__((ext_vector_type(2)));

#if __has_builtin(__builtin_elementwise_fma)
#define FMA2(a, b, c) __builtin_elementwise_fma((a), (b), (c))
#else
#define FMA2(a, b, c) ((a) * (b) + (c))
#endif

typedef const unsigned int __attribute__((address_space(1))) u32_g;
typedef unsigned int __attribute__((address_space(3))) u32_s;
#define GLDS16(gp, lp) __builtin_amdgcn_global_load_lds((u32_g*)(gp), (u32_s*)(lp), 16, 0, 0)

namespace {
constexpr int Bn = 2, Cn = 64, Dn = 16, Hn = 64, Wn = 64;
constexpr int Gn = 2, Kn = 27, GCn = 32;
constexpr int DHW = Dn * Hn * Wn;                 // 65536
constexpr int OCn = 216;                          // 162 off + 54 mask
constexpr int PD = 18, PH = 66, PW = 66;
constexpr float EPS = 1e-5f;

// conv patch: 3d x 4h x 66w rows of 128B (64ch bf16)
constexpr int PROWS = 12 * 66;                    // 792
constexpr int PATCH_B = PROWS * 128;              // 101376
constexpr int ABUF_B = 16384;                     // 256 oc x 32 k x 2B

constexpr size_t XPADH_OFF = 0;
constexpr size_t XPADH_B   = (size_t)Bn * PD * PH * PW * Cn * 2;   // 20,072,448
constexpr size_t WFRAG_OFF = XPADH_OFF + XPADH_B;
constexpr size_t WFRAG_B   = (size_t)54 * 16 * 64 * 16;            // 884,736
constexpr size_t WV_OFF    = WFRAG_OFF + WFRAG_B;
constexpr size_t WV_B      = 64 * 64 * 4;
constexpr size_t CONV_OFF  = WV_OFF + WV_B;
constexpr size_t CONV_B    = (size_t)Bn * OCn * DHW * 2;           // 56,623,104
constexpr size_t V_OFF     = CONV_OFF + CONV_B;
constexpr size_t V_B       = (size_t)Bn * Gn * DHW * GCn * 2;      // 16,777,216 (bf16)
constexpr size_t SAMP_OFF  = V_OFF + V_B;
constexpr size_t SAMP_B    = (size_t)Bn * Gn * DHW * GCn * 2;      // 16,777,216
constexpr size_t STAT_OFF  = SAMP_OFF + SAMP_B;
// t (bf16, 16.7MB) reuses the xpadh region (dead after conv_mfma)
}

__device__ inline float b2f(short s) {
  union { float f; unsigned u; } x; x.u = ((unsigned)(unsigned short)s) << 16; return x.f;
}
__device__ inline short f2b(float f) {
  __hip_bfloat16 h = __float2bfloat16(f);
  union { __hip_bfloat16 h; short s; } x; x.h = h; return x.s;
}
__device__ inline int iclamp(int v, int lo, int hi) { return v < lo ? lo : (v > hi ? hi : v); }
__device__ inline f32x2 up2(unsigned u) {
  f32x2 r; r.x = __uint_as_float(u << 16); r.y = __uint_as_float(u & 0xffff0000u); return r;
}

// ---- zero-fill padded input volume ----
__global__ __launch_bounds__(256) void zerofill(uint4* __restrict__ p, int n16) {
  int i = blockIdx.x * 256 + threadIdx.x;
  if (i < n16) p[i] = make_uint4(0, 0, 0, 0);
}

// ---- transpose-pad x [b,c,d,h,w] f32 -> xpadh [b,dz,hy,wx,c] bf16 (interior) ----
// direct: 32 positions x 8 channel-groups per 256-thread block
__global__ __launch_bounds__(256) void fillpad(const float* __restrict__ x,
                                               __hip_bfloat16* __restrict__ xpadh) {
  int tid = threadIdx.x;
  int w5 = tid & 31, cq = tid >> 5;
  int p = blockIdx.x * 32 + w5;
  int b = blockIdx.y;
  int w = p & 63, h = (p >> 6) & 63, d = p >> 12;
  const float* xb = x + ((size_t)b * 64 + cq * 8) * DHW + p;
  short8 o8;
#pragma unroll
  for (int j = 0; j < 8; ++j) o8[j] = f2b(xb[(size_t)j * DHW]);
  __hip_bfloat16* ob = xpadh + (size_t)b * (PD * PH * PW * 64)
      + ((((size_t)(d + 1) * 66) + (h + 1)) * 66 + (w + 1)) * 64 + cq * 8;
  *(short8*)ob = o8;
}

// ---- fold pre 1x1 into conv weights (MFMA fragment order) and value projection ----
__global__ __launch_bounds__(256) void fold_weights(
    const float* __restrict__ pre_w, const float* __restrict__ in_proj_w,
    const float* __restrict__ off_w, const float* __restrict__ mask_w,
    short8* __restrict__ Wfrag, float* __restrict__ Wv) {
  int i = blockIdx.x * 256 + threadIdx.x;
  if (i < 64 * 64) {
    int o = i >> 6, c = i & 63;
    float s = 0.f;
    for (int cp = 0; cp < 64; ++cp) s += in_proj_w[o * 64 + cp] * pre_w[cp * 64 + c];
    Wv[i] = s;
    return;
  }
  int t = i - 64 * 64;
  if (t >= 54 * 16 * 64) return;
  int l = t & 63; int rest = t >> 6;
  int mt = rest & 15; int ks = rest >> 4;
  int oc = mt * 16 + (l & 15);
  int tap = ks >> 1;
  int c0 = (ks & 1) * 32 + (l >> 4) * 8;
  float vals[8] = {0.f, 0.f, 0.f, 0.f, 0.f, 0.f, 0.f, 0.f};
  if (oc < OCn) {
    const float* cw = (oc < 162) ? (off_w + (size_t)oc * 64 * 27)
                                 : (mask_w + (size_t)(oc - 162) * 64 * 27);
#pragma unroll 1
    for (int cp = 0; cp < 64; ++cp) {
      float wv = cw[cp * 27 + tap];
      const float* pr = pre_w + cp * 64 + c0;
#pragma unroll
      for (int j = 0; j < 8; ++j) vals[j] += wv * pr[j];
    }
  }
  short8 o8;
#pragma unroll
  for (int j = 0; j < 8; ++j) o8[j] = f2b(vals[j]);
  Wfrag[t] = o8;
}

// ---- value projection v = (in_proj_w @ pre_w) @ x + b, bf16 layout [b,g,p,32] ----
__global__ __launch_bounds__(256) void vproj(
    const float* __restrict__ x, const float* __restrict__ Wv,
    const float* __restrict__ vb, __hip_bfloat16* __restrict__ v) {
  int p = blockIdx.x * 256 + threadIdx.x;
  int b = blockIdx.y;
  const float* xb = x + (size_t)b * Cn * DHW;
  float xv[Cn];
#pragma unroll
  for (int c = 0; c < Cn; ++c) xv[c] = xb[c * DHW + p];
#pragma unroll 1
  for (int g = 0; g < Gn; ++g) {
    float vo[GCn];
#pragma unroll
    for (int j = 0; j < GCn; ++j) {
      int o = g * GCn + j;
      float s = vb[o];
#pragma unroll
      for (int c = 0; c < Cn; ++c) s += Wv[o * Cn + c] * xv[c];
      vo[j] = s;
    }
    short8* dst = (short8*)(v + ((size_t)(b * Gn + g) * DHW + p) * GCn);
#pragma unroll
    for (int q = 0; q < 4; ++q) {
      short8 o8;
#pragma unroll
      for (int j = 0; j < 8; ++j) o8[j] = f2b(vo[q * 8 + j]);
      dst[q] = o8;
    }
  }
}

// ---- MFMA implicit-GEMM 3x3x3 conv: M=256(216) oc x N=128 pos, K=1728 ----
// 512 threads = 8 waves, 64x64 wave tiles; A double-buffered via global_load_lds.
__global__ __launch_bounds__(512, 1) void conv_mfma(
    const char* __restrict__ xpadh, const uint4* __restrict__ wfrag,
    const float* __restrict__ off_b, const float* __restrict__ mask_b,
    __hip_bfloat16* __restrict__ convout) {
  __shared__ char lds[PATCH_B + 2 * ABUF_B];       // 134,144 B
  int tid = threadIdx.x;
  int h0 = blockIdx.x * 2, d = blockIdx.y, b = blockIdx.z;

  // async-stage A[0]: wave-uniform LDS base + lane*16 (linear), per-lane global src
  {
    char* a0 = lds + PATCH_B + ((tid >> 6) << 10);
    GLDS16(wfrag + tid, a0);
    GLDS16(wfrag + tid + 512, a0 + 8192);
  }
  // stage patch (all 27 taps' B-data), XOR-swizzled rows
  const char* xb = xpadh + (size_t)b * (PD * PH * PW * 128);
  for (int idx = tid; idx < PROWS * 8; idx += 512) {
    int s = idx >> 3, slot = idx & 7;
    int r12 = s / 66, wx = s - r12 * 66;
    int dp = r12 >> 2, hp = r12 & 3;
    const char* g = xb + ((((size_t)(d + dp)) * 66 + (h0 + hp)) * 66 + wx) * 128 + slot * 16;
    *(uint4*)(lds + s * 128 + ((slot ^ (s & 7)) << 4)) = *(const uint4*)g;
  }
  __syncthreads();

  int wid = tid >> 6, l = tid & 63;
  int wm = wid & 3, wn = wid >> 2;                 // wm: 64-oc quarter; wn: h-row (0..1)
  int lm = l & 15, lk = l >> 4;
  f32x4 acc[4][4];
#pragma unroll
  for (int mt = 0; mt < 4; ++mt)
#pragma unroll
    for (int nt = 0; nt < 4; ++nt) acc[mt][nt] = (f32x4){0.f, 0.f, 0.f, 0.f};

#pragma unroll 1
  for (int ks = 0; ks < 54; ++ks) {
    int cur = ks & 1;
    if (ks < 53) {                                 // issue next A-tile DMA early
      char* an = lds + PATCH_B + (cur ^ 1) * ABUF_B + (wid << 10);
      const uint4* gsrc = wfrag + (ks + 1) * 1024;
      GLDS16(gsrc + tid, an);
      GLDS16(gsrc + tid + 512, an + 8192);
    }
    int tap = ks >> 1;
    int dd = tap / 9, rem = tap - dd * 9, dh = rem / 3, dw = rem - dh * 3;
    int srow = (dd * 4 + wn + dh) * 66 + dw;
    int uslot = 4 * cur + lk;
    short8 bfr[4];
#pragma unroll
    for (int nt = 0; nt < 4; ++nt) {
      int sr = srow + nt * 16 + lm;
      bfr[nt] = *(const short8*)(lds + sr * 128 + ((uslot ^ (sr & 7)) << 4));
    }
    const char* abase = lds + PATCH_B + cur * ABUF_B + ((wm * 4) * 64 + l) * 16;
    short8 afr[4];
#pragma unroll
    for (int mt = 0; mt < 4; ++mt)
      afr[mt] = *(const short8*)(abase + mt * 1024);
#pragma unroll
    for (int mt = 0; mt < 4; ++mt)
#pragma unroll
      for (int nt = 0; nt < 4; ++nt)
        acc[mt][nt] = __builtin_amdgcn_mfma_f32_16x16x32_bf16(afr[mt], bfr[nt], acc[mt][nt], 0, 0, 0);
    __syncthreads();                               // drains this phase's DMA; cur readers done
  }

  int pbase = d * 4096 + (h0 + wn) * 64;
#pragma unroll
  for (int mt = 0; mt < 4; ++mt) {
    int oc0 = wm * 64 + mt * 16 + lk * 4;
#pragma unroll
    for (int r = 0; r < 4; ++r) {
      int oc = oc0 + r;
      if (oc < OCn) {
        float bias = (oc < 162) ? off_b[oc] : mask_b[oc - 162];
        size_t orow = ((size_t)b * OCn + oc) * DHW + pbase;
#pragma unroll
        for (int nt = 0; nt < 4; ++nt)
          convout[orow + nt * 16 + lm] = __float2bfloat16(acc[mt][nt][r] + bias);
      }
    }
  }
}

// ---- deformable trilinear sampling + fused mask softmax ----
__global__ __launch_bounds__(256) void dcn_sample(
    const __hip_bfloat16* __restrict__ convout, const __hip_bfloat16* __restrict__ v,
    __hip_bfloat16* __restrict__ sampled) {
  __shared__ short offm[108 * 128];                // 27,648 B
  int tid = threadIdx.x;
  int bg = blockIdx.y;
  int b = bg >> 1, g = bg & 1;
  int p0 = blockIdx.x * 128;

  const __hip_bfloat16* cb = convout + (size_t)b * OCn * DHW;
#pragma unroll 1
  for (int idx = tid; idx < 108 * 16; idx += 256) {
    int row = idx >> 4, col = idx & 15;
    int oc = (row < 81) ? (g * 81 + row) : (162 + g * Kn + (row - 81));
    uint4 vv = *(const uint4*)(cb + (size_t)oc * DHW + p0 + col * 8);
    *(uint4*)(offm + row * 128 + col * 8) = vv;
  }
  __syncthreads();

  int pl = tid >> 1, half = tid & 1;
  int p = p0 + pl;
  int w = p & 63, h = (p >> 6) & 63, d = p >> 12;

  // softmax without max-shift: logits are small conv outputs (exp-safe), shift-invariant
  float msum = 0.f;
#pragma unroll 1
  for (int k = 0; k < Kn; ++k) msum += __expf(b2f(offm[(81 + k) * 128 + pl]));
  float rs = 1.f / msum;

  f32x2 acc[8];
#pragma unroll
  for (int q = 0; q < 8; ++q) acc[q] = (f32x2){0.f, 0.f};
  const char* vg = (const char*)v + ((size_t)bg * DHW * GCn + half * 16) * 2;

#pragma unroll 1
  for (int k = 0; k < Kn; ++k) {
    float offd = b2f(offm[(3 * k + 0) * 128 + pl]);
    float offh = b2f(offm[(3 * k + 1) * 128 + pl]);
    float offw = b2f(offm[(3 * k + 2) * 128 + pl]);
    float pd = (float)(d + (k / 9) - 1) + offd * 0.5f;
    float ph = (float)(h + ((k / 3) % 3) - 1) + offh;
    float pw = (float)(w + (k % 3) - 1) + offw;
    float fd = floorf(pd), fh = floorf(ph), fw = floorf(pw);
    float td = pd - fd, th = ph - fh, tw = pw - fw;
    int d0 = (int)fd, h0 = (int)fh, w0 = (int)fw;
    float mk = __expf(b2f(offm[(81 + k) * 128 + pl])) * rs;

    float wd0 = ((unsigned)d0 < (unsigned)Dn) ? (1.f - td) * mk : 0.f;
    float wd1 = ((unsigned)(d0 + 1) < (unsigned)Dn) ? td * mk : 0.f;
    float wh0 = ((unsigned)h0 < (unsigned)Hn) ? (1.f - th) : 0.f;
    float wh1 = ((unsigned)(h0 + 1) < (unsigned)Hn) ? th : 0.f;
    float ww0 = ((unsigned)w0 < (unsigned)Wn) ? (1.f - tw) : 0.f;
    float ww1 = ((unsigned)(w0 + 1) < (unsigned)Wn) ? tw : 0.f;
    int dr0 = iclamp(d0, 0, Dn - 1) * 4096, dr1 = iclamp(d0 + 1, 0, Dn - 1) * 4096;
    int hr0 = iclamp(h0, 0, Hn - 1) * 64,   hr1 = iclamp(h0 + 1, 0, Hn - 1) * 64;
    int wc0 = iclamp(w0, 0, Wn - 1),        wc1 = iclamp(w0 + 1, 0, Wn - 1);
    float wdh00 = wd0 * wh0, wdh01 = wd0 * wh1, wdh10 = wd1 * wh0, wdh11 = wd1 * wh1;

#define CORNER(RD, RH, WC, WT)                                          \
    {                                                                   \
      float wt_ = (WT);                                                 \
      f32x2 w2_ = {wt_, wt_};                                           \
      int boff_ = ((RD) + (RH) + (WC)) << 6;                            \
      const uint4* s_ = (const uint4*)(vg + boff_);                     \
      uint4 ua_ = s_[0], ub_ = s_[1];                                   \
      acc[0] = FMA2(up2(ua_.x), w2_, acc[0]);                           \
      acc[1] = FMA2(up2(ua_.y), w2_, acc[1]);                           \
      acc[2] = FMA2(up2(ua_.z), w2_, acc[2]);                           \
      acc[3] = FMA2(up2(ua_.w), w2_, acc[3]);                           \
      acc[4] = FMA2(up2(ub_.x), w2_, acc[4]);                           \
      acc[5] = FMA2(up2(ub_.y), w2_, acc[5]);                           \
      acc[6] = FMA2(up2(ub_.z), w2_, acc[6]);                           \
      acc[7] = FMA2(up2(ub_.w), w2_, acc[7]);                           \
    }
    CORNER(dr0, hr0, wc0, wdh00 * ww0)
    CORNER(dr0, hr0, wc1, wdh00 * ww1)
    CORNER(dr0, hr1, wc0, wdh01 * ww0)
    CORNER(dr0, hr1, wc1, wdh01 * ww1)
    CORNER(dr1, hr0, wc0, wdh10 * ww0)
    CORNER(dr1, hr0, wc1, wdh10 * ww1)
    CORNER(dr1, hr1, wc0, wdh11 * ww0)
    CORNER(dr1, hr1, wc1, wdh11 * ww1)
#undef CORNER
  }

  const float* af = (const float*)acc;
  short8* dst = (short8*)(sampled + ((size_t)bg * DHW + p) * GCn + half * 16);
#pragma unroll
  for (int q = 0; q < 2; ++q) {
    short8 o8;
#pragma unroll
    for (int j = 0; j < 8; ++j) o8[j] = f2b(af[q * 8 + j]);
    dst[q] = o8;
  }
}

// ---- out_proj: t (bf16, in ws) ----
__global__ __launch_bounds__(256) void outproj(
    const __hip_bfloat16* __restrict__ sampled, const float* __restrict__ Wout,
    const float* __restrict__ ob, __hip_bfloat16* __restrict__ t) {
  int p = blockIdx.x * 256 + threadIdx.x;
  int b = blockIdx.y;
  float sv[Cn];
#pragma unroll
  for (int g = 0; g < Gn; ++g) {
    const short8* src = (const short8*)(sampled) + ((size_t)(b * Gn + g) * DHW + p) * 4;
#pragma unroll
    for (int q = 0; q < 4; ++q) {
      short8 s8 = src[q];
#pragma unroll
      for (int j = 0; j < 8; ++j) sv[g * GCn + q * 8 + j] = b2f(s8[j]);
    }
  }
#pragma unroll 1
  for (int o = 0; o < Cn; ++o) {
    float s = ob[o];
#pragma unroll
    for (int c = 0; c < Cn; ++c) s += Wout[o * Cn + c] * sv[c];
    t[((size_t)b * Cn + o) * DHW + p] = __float2bfloat16(s);
  }
}

// ---- per-(b,c) instance-norm stats (bf16 input, vectorized) ----
__global__ __launch_bounds__(256) void stats_k(const __hip_bfloat16* __restrict__ t,
                                               float* __restrict__ stat) {
  int bc = blockIdx.x;
  const short8* tc = (const short8*)(t + (size_t)bc * DHW);
  float s = 0.f, ss = 0.f;
  for (int i = threadIdx.x; i < DHW / 8; i += 256) {
    short8 s8 = tc[i];
#pragma unroll
    for (int j = 0; j < 8; ++j) { float xv = b2f(s8[j]); s += xv; ss += xv * xv; }
  }
#pragma unroll
  for (int o = 32; o > 0; o >>= 1) { s += __shfl_down(s, o); ss += __shfl_down(ss, o); }
  __shared__ float ls[4], lss[4];
  int wid = threadIdx.x >> 6;
  if ((threadIdx.x & 63) == 0) { ls[wid] = s; lss[wid] = ss; }
  __syncthreads();
  if (threadIdx.x == 0) {
    float S = ls[0] + ls[1] + ls[2] + ls[3];
    float SS = lss[0] + lss[1] + lss[2] + lss[3];
    float mu = S / (float)DHW;
    float var = SS / (float)DHW - mu * mu;
    stat[bc * 2 + 0] = mu;
    stat[bc * 2 + 1] = rsqrtf(var + EPS);
  }
}

// ---- norm + gelu + post 1x1 + gated residual ----
__global__ __launch_bounds__(256) void finalk(
    const __hip_bfloat16* __restrict__ t, const float* __restrict__ x,
    const float* __restrict__ stat,
    const float* __restrict__ gamma, const float* __restrict__ beta,
    const float* __restrict__ Wpost, const float* __restrict__ gate, float* out) {
  int p = blockIdx.x * 256 + threadIdx.x;
  int b = blockIdx.y;
  float sg = 1.f / (1.f + __expf(-gate[0]));
  float nv[Cn];
#pragma unroll
  for (int c = 0; c < Cn; ++c) {
    float mu = stat[(b * Cn + c) * 2 + 0];
    float rstd = stat[(b * Cn + c) * 2 + 1];
    float tv = b2f(((const short*)t)[((size_t)b * Cn + c) * DHW + p]);
    float yv = (tv - mu) * rstd * gamma[c] + beta[c];
    float u = 0.7978845608028654f * (yv + 0.044715f * yv * yv * yv);
    float e = __expf(2.f * u);
    float th = 1.f - 2.f / (e + 1.f);
    nv[c] = 0.5f * yv * (1.f + th);
  }
#pragma unroll 1
  for (int o = 0; o < Cn; ++o) {
    float s = 0.f;
#pragma unroll
    for (int c = 0; c < Cn; ++c) s += Wpost[o * Cn + c] * nv[c];
    size_t i = ((size_t)b * Cn + o) * DHW + p;
    out[i] = x[i] + sg * s;
  }
}

extern "C" void kernel_launch(void* const* d_in, const int* in_sizes, int n_in,
                              void* d_out, int out_size, void* d_ws, size_t ws_size,
                              hipStream_t stream) {
  const float* x          = (const float*)d_in[0];
  const float* gate       = (const float*)d_in[1];
  const float* pre_w      = (const float*)d_in[2];
  const float* post_w     = (const float*)d_in[3];
  const float* in_proj_w  = (const float*)d_in[4];
  const float* in_proj_b  = (const float*)d_in[5];
  const float* out_proj_w = (const float*)d_in[6];
  const float* out_proj_b = (const float*)d_in[7];
  const float* off_w      = (const float*)d_in[8];
  const float* off_b      = (const float*)d_in[9];
  const float* mask_w     = (const float*)d_in[10];
  const float* mask_b     = (const float*)d_in[11];
  const float* in_gamma   = (const float*)d_in[12];
  const float* in_beta    = (const float*)d_in[13];

  char* ws = (char*)d_ws;
  __hip_bfloat16* xpadh = (__hip_bfloat16*)(ws + XPADH_OFF);
  short8* Wfrag  = (short8*)(ws + WFRAG_OFF);
  float* Wv      = (float*)(ws + WV_OFF);
  __hip_bfloat16* convout = (__hip_bfloat16*)(ws + CONV_OFF);
  __hip_bfloat16* v       = (__hip_bfloat16*)(ws + V_OFF);
  __hip_bfloat16* sampled = (__hip_bfloat16*)(ws + SAMP_OFF);
  float* stat    = (float*)(ws + STAT_OFF);
  __hip_bfloat16* t = (__hip_bfloat16*)(ws + XPADH_OFF);   // reuses xpadh region
  float* out = (float*)d_out;

  int zf16 = (int)(XPADH_B / 16);
  zerofill<<<(zf16 + 255) / 256, 256, 0, stream>>>((uint4*)xpadh, zf16);
  fillpad<<<dim3(DHW / 32, Bn), 256, 0, stream>>>(x, xpadh);
  int foldN = (64 * 64 + 54 * 16 * 64 + 255) / 256;
  fold_weights<<<foldN, 256, 0, stream>>>(pre_w, in_proj_w, off_w, mask_w, Wfrag, Wv);
  vproj<<<dim3(DHW / 256, Bn), 256, 0, stream>>>(x, Wv, in_proj_b, v);
  conv_mfma<<<dim3(32, 16, 2), 512, 0, stream>>>((const char*)xpadh, (const uint4*)Wfrag,
                                                 off_b, mask_b, convout);
  dcn_sample<<<dim3(DHW / 128, Bn * Gn), 256, 0, stream>>>(convout, v, sampled);
  outproj<<<dim3(DHW / 256, Bn), 256, 0, stream>>>(sampled, out_proj_w, out_proj_b, t);
  stats_k<<<Bn * Cn, 256, 0, stream>>>(t, stat);
  finalk<<<dim3(DHW / 256, Bn), 256, 0, stream>>>(t, x, stat, in_gamma, in_beta,
                                                  post_w, gate, out);
}

// Round 6
// 517.717 us; speedup vs baseline: 4.2423x; 1.0128x over previous
//
#include <hip/hip_runtime.h>
#include <hip/hip_bf16.h>

typedef short short8 __attribute__((ext_vector_type(8)));
typedef float f32x4 __attribute__((ext_vector_type(4)));
typedef float f32x2 __attribute__((ext_vector_type(2)));

#if __has_builtin(__builtin_elementwise_fma)
#define FMA2(a, b, c) __builtin_elementwise_fma((a), (b), (c))
#else
#define FMA2(a, b, c) ((a) * (b) + (c))
#endif

typedef const unsigned int __attribute__((address_space(1))) u32_g;
typedef unsigned int __attribute__((address_space(3))) u32_s;
#define GLDS16(gp, lp) __builtin_amdgcn_global_load_lds((u32_g*)(gp), (u32_s*)(lp), 16, 0, 0)

namespace {
constexpr int Bn = 2, Cn = 64, Dn = 16, Hn = 64, Wn = 64;
constexpr int Gn = 2, Kn = 27, GCn = 32;
constexpr int DHW = Dn * Hn * Wn;                 // 65536
constexpr int OCn = 216;                          // 162 off + 54 mask
constexpr int PD = 18, PH = 66, PW = 66;
constexpr float EPS = 1e-5f;

// conv patch: 3d x 4h x 66w rows of 128B (64ch bf16)
constexpr int PROWS = 12 * 66;                    // 792
constexpr int PATCH_B = PROWS * 128;              // 101376
constexpr int ABUF_B = 16384;                     // 256 oc x 32 k x 2B

constexpr size_t XPADH_OFF = 0;
constexpr size_t XPADH_B   = (size_t)Bn * PD * PH * PW * Cn * 2;   // 20,072,448
constexpr size_t WFRAG_OFF = XPADH_OFF + XPADH_B;
constexpr size_t WFRAG_B   = (size_t)54 * 16 * 64 * 16;            // 884,736
constexpr size_t WV_OFF    = WFRAG_OFF + WFRAG_B;
constexpr size_t WV_B      = 64 * 64 * 4;
constexpr size_t CONV_OFF  = WV_OFF + WV_B;
constexpr size_t CONV_B    = (size_t)Bn * OCn * DHW * 2;           // 56,623,104
constexpr size_t V_OFF     = CONV_OFF + CONV_B;
constexpr size_t V_B       = (size_t)Bn * Gn * DHW * GCn * 2;      // 16,777,216 (bf16)
constexpr size_t SAMP_OFF  = V_OFF + V_B;
constexpr size_t SAMP_B    = (size_t)Bn * Gn * DHW * GCn * 2;      // 16,777,216
constexpr size_t STAT_OFF  = SAMP_OFF + SAMP_B;
// t (bf16, 16.7MB) reuses the xpadh region (dead after conv_mfma)
}

__device__ inline float b2f(short s) {
  union { float f; unsigned u; } x; x.u = ((unsigned)(unsigned short)s) << 16; return x.f;
}
__device__ inline short f2b(float f) {
  __hip_bfloat16 h = __float2bfloat16(f);
  union { __hip_bfloat16 h; short s; } x; x.h = h; return x.s;
}
__device__ inline int iclamp(int v, int lo, int hi) { return v < lo ? lo : (v > hi ? hi : v); }
__device__ inline f32x2 up2(unsigned u) {
  f32x2 r; r.x = __uint_as_float(u << 16); r.y = __uint_as_float(u & 0xffff0000u); return r;
}

// ---- zero-fill padded input volume ----
__global__ __launch_bounds__(256) void zerofill(uint4* __restrict__ p, int n16) {
  int i = blockIdx.x * 256 + threadIdx.x;
  if (i < n16) p[i] = make_uint4(0, 0, 0, 0);
}

// ---- transpose-pad x [b,c,d,h,w] f32 -> xpadh [b,dz,hy,wx,c] bf16 (interior) ----
__global__ __launch_bounds__(256) void fillpad(const float* __restrict__ x,
                                               __hip_bfloat16* __restrict__ xpadh) {
  int tid = threadIdx.x;
  int w5 = tid & 31, cq = tid >> 5;
  int p = blockIdx.x * 32 + w5;
  int b = blockIdx.y;
  int w = p & 63, h = (p >> 6) & 63, d = p >> 12;
  const float* xb = x + ((size_t)b * 64 + cq * 8) * DHW + p;
  short8 o8;
#pragma unroll
  for (int j = 0; j < 8; ++j) o8[j] = f2b(xb[(size_t)j * DHW]);
  __hip_bfloat16* ob = xpadh + (size_t)b * (PD * PH * PW * 64)
      + ((((size_t)(d + 1) * 66) + (h + 1)) * 66 + (w + 1)) * 64 + cq * 8;
  *(short8*)ob = o8;
}

// ---- fold pre 1x1 into conv weights (MFMA fragment order) and value projection ----
__global__ __launch_bounds__(256) void fold_weights(
    const float* __restrict__ pre_w, const float* __restrict__ in_proj_w,
    const float* __restrict__ off_w, const float* __restrict__ mask_w,
    short8* __restrict__ Wfrag, float* __restrict__ Wv) {
  int i = blockIdx.x * 256 + threadIdx.x;
  if (i < 64 * 64) {
    int o = i >> 6, c = i & 63;
    float s = 0.f;
    for (int cp = 0; cp < 64; ++cp) s += in_proj_w[o * 64 + cp] * pre_w[cp * 64 + c];
    Wv[i] = s;
    return;
  }
  int t = i - 64 * 64;
  if (t >= 54 * 16 * 64) return;
  int l = t & 63; int rest = t >> 6;
  int mt = rest & 15; int ks = rest >> 4;
  int oc = mt * 16 + (l & 15);
  int tap = ks >> 1;
  int c0 = (ks & 1) * 32 + (l >> 4) * 8;
  float vals[8] = {0.f, 0.f, 0.f, 0.f, 0.f, 0.f, 0.f, 0.f};
  if (oc < OCn) {
    const float* cw = (oc < 162) ? (off_w + (size_t)oc * 64 * 27)
                                 : (mask_w + (size_t)(oc - 162) * 64 * 27);
#pragma unroll 1
    for (int cp = 0; cp < 64; ++cp) {
      float wv = cw[cp * 27 + tap];
      const float* pr = pre_w + cp * 64 + c0;
#pragma unroll
      for (int j = 0; j < 8; ++j) vals[j] += wv * pr[j];
    }
  }
  short8 o8;
#pragma unroll
  for (int j = 0; j < 8; ++j) o8[j] = f2b(vals[j]);
  Wfrag[t] = o8;
}

// ---- value projection v = (in_proj_w @ pre_w) @ x + b, bf16 layout [b,g,p,32] ----
__global__ __launch_bounds__(256) void vproj(
    const float* __restrict__ x, const float* __restrict__ Wv,
    const float* __restrict__ vb, __hip_bfloat16* __restrict__ v) {
  int p = blockIdx.x * 256 + threadIdx.x;
  int b = blockIdx.y;
  const float* xb = x + (size_t)b * Cn * DHW;
  float xv[Cn];
#pragma unroll
  for (int c = 0; c < Cn; ++c) xv[c] = xb[c * DHW + p];
#pragma unroll 1
  for (int g = 0; g < Gn; ++g) {
    float vo[GCn];
#pragma unroll
    for (int j = 0; j < GCn; ++j) {
      int o = g * GCn + j;
      float s = vb[o];
#pragma unroll
      for (int c = 0; c < Cn; ++c) s += Wv[o * Cn + c] * xv[c];
      vo[j] = s;
    }
    short8* dst = (short8*)(v + ((size_t)(b * Gn + g) * DHW + p) * GCn);
#pragma unroll
    for (int q = 0; q < 4; ++q) {
      short8 o8;
#pragma unroll
      for (int j = 0; j < 8; ++j) o8[j] = f2b(vo[q * 8 + j]);
      dst[q] = o8;
    }
  }
}

// ---- MFMA implicit-GEMM 3x3x3 conv: M=256(216) oc x N=128 pos, K=1728 ----
// 512 threads = 8 waves, 64x64 wave tiles; A dbuf via global_load_lds; B prefetch.
__global__ __launch_bounds__(512, 1) void conv_mfma(
    const char* __restrict__ xpadh, const uint4* __restrict__ wfrag,
    const float* __restrict__ off_b, const float* __restrict__ mask_b,
    __hip_bfloat16* __restrict__ convout) {
  __shared__ char lds[PATCH_B + 2 * ABUF_B];       // 134,144 B
  int tid = threadIdx.x;
  int h0 = blockIdx.x * 2, d = blockIdx.y, b = blockIdx.z;

  {
    char* a0 = lds + PATCH_B + ((tid >> 6) << 10);
    GLDS16(wfrag + tid, a0);
    GLDS16(wfrag + tid + 512, a0 + 8192);
  }
  const char* xb = xpadh + (size_t)b * (PD * PH * PW * 128);
  for (int idx = tid; idx < PROWS * 8; idx += 512) {
    int s = idx >> 3, slot = idx & 7;
    int r12 = s / 66, wx = s - r12 * 66;
    int dp = r12 >> 2, hp = r12 & 3;
    const char* g = xb + ((((size_t)(d + dp)) * 66 + (h0 + hp)) * 66 + wx) * 128 + slot * 16;
    *(uint4*)(lds + s * 128 + ((slot ^ (s & 7)) << 4)) = *(const uint4*)g;
  }
  __syncthreads();

  int wid = tid >> 6, l = tid & 63;
  int wm = wid & 3, wn = wid >> 2;
  int lm = l & 15, lk = l >> 4;
  f32x4 acc[4][4];
#pragma unroll
  for (int mt = 0; mt < 4; ++mt)
#pragma unroll
    for (int nt = 0; nt < 4; ++nt) acc[mt][nt] = (f32x4){0.f, 0.f, 0.f, 0.f};

  // prefetched B fragments for current step (patch is static after first barrier)
  short8 bfr[4];
  {
    int srow = (0 * 4 + wn + 0) * 66 + 0;          // ks=0: tap 0, uslot=lk
#pragma unroll
    for (int nt = 0; nt < 4; ++nt) {
      int sr = srow + nt * 16 + lm;
      bfr[nt] = *(const short8*)(lds + sr * 128 + ((lk ^ (sr & 7)) << 4));
    }
  }

#pragma unroll 2
  for (int ks = 0; ks < 54; ++ks) {
    int cur = ks & 1;
    if (ks < 53) {                                 // next A-tile DMA
      char* an = lds + PATCH_B + (cur ^ 1) * ABUF_B + (wid << 10);
      const uint4* gsrc = wfrag + (ks + 1) * 1024;
      GLDS16(gsrc + tid, an);
      GLDS16(gsrc + tid + 512, an + 8192);
    }
    const char* abase = lds + PATCH_B + cur * ABUF_B + ((wm * 4) * 64 + l) * 16;
    short8 afr[4];
#pragma unroll
    for (int mt = 0; mt < 4; ++mt)
      afr[mt] = *(const short8*)(abase + mt * 1024);
    short8 bnx[4];
    if (ks < 53) {                                 // prefetch next step's B (static patch)
      int t2 = (ks + 1) >> 1;
      int dd = t2 / 9, rem = t2 - dd * 9, dh = rem / 3, dw = rem - dh * 3;
      int srow = (dd * 4 + wn + dh) * 66 + dw;
      int uslot = 4 * ((ks + 1) & 1) + lk;
#pragma unroll
      for (int nt = 0; nt < 4; ++nt) {
        int sr = srow + nt * 16 + lm;
        bnx[nt] = *(const short8*)(lds + sr * 128 + ((uslot ^ (sr & 7)) << 4));
      }
    }
    __builtin_amdgcn_s_setprio(1);
#pragma unroll
    for (int mt = 0; mt < 4; ++mt)
#pragma unroll
      for (int nt = 0; nt < 4; ++nt)
        acc[mt][nt] = __builtin_amdgcn_mfma_f32_16x16x32_bf16(afr[mt], bfr[nt], acc[mt][nt], 0, 0, 0);
    __builtin_amdgcn_s_setprio(0);
#pragma unroll
    for (int nt = 0; nt < 4; ++nt) bfr[nt] = bnx[nt];
    __syncthreads();                               // drains DMA; all waves done with cur
  }

  int pbase = d * 4096 + (h0 + wn) * 64;
#pragma unroll
  for (int mt = 0; mt < 4; ++mt) {
    int oc0 = wm * 64 + mt * 16 + lk * 4;
#pragma unroll
    for (int r = 0; r < 4; ++r) {
      int oc = oc0 + r;
      if (oc < OCn) {
        float bias = (oc < 162) ? off_b[oc] : mask_b[oc - 162];
        size_t orow = ((size_t)b * OCn + oc) * DHW + pbase;
#pragma unroll
        for (int nt = 0; nt < 4; ++nt)
          convout[orow + nt * 16 + lm] = __float2bfloat16(acc[mt][nt][r] + bias);
      }
    }
  }
}

// ---- deformable trilinear sampling + fused mask softmax ----
// 4 threads per (p,g): 8 channels each; 64 positions/block (13.8KB LDS -> high occ)
__global__ __launch_bounds__(256) void dcn_sample(
    const __hip_bfloat16* __restrict__ convout, const __hip_bfloat16* __restrict__ v,
    __hip_bfloat16* __restrict__ sampled) {
  __shared__ short offm[108 * 64];                 // 13,824 B
  int tid = threadIdx.x;
  int bg = blockIdx.y;
  int b = bg >> 1, g = bg & 1;
  int p0 = blockIdx.x * 64;

  const __hip_bfloat16* cb = convout + (size_t)b * OCn * DHW;
#pragma unroll 1
  for (int idx = tid; idx < 108 * 8; idx += 256) {
    int row = idx >> 3, col = idx & 7;
    int oc = (row < 81) ? (g * 81 + row) : (162 + g * Kn + (row - 81));
    *(uint4*)(offm + row * 64 + col * 8) = *(const uint4*)(cb + (size_t)oc * DHW + p0 + col * 8);
  }
  __syncthreads();

  int pl = tid >> 2, q = tid & 3;
  int p = p0 + pl;
  int w = p & 63, h = (p >> 6) & 63, d = p >> 12;

  // softmax without max-shift: logits are small conv outputs (exp-safe), shift-invariant
  float msum = 0.f;
#pragma unroll 1
  for (int k = 0; k < Kn; ++k) msum += __expf(b2f(offm[(81 + k) * 64 + pl]));
  float rs = 1.f / msum;

  f32x2 acc[4];
#pragma unroll
  for (int j = 0; j < 4; ++j) acc[j] = (f32x2){0.f, 0.f};
  const char* vg = (const char*)v + ((size_t)bg * DHW * GCn + q * 8) * 2;

#pragma unroll 1
  for (int k = 0; k < Kn; ++k) {
    float offd = b2f(offm[(3 * k + 0) * 64 + pl]);
    float offh = b2f(offm[(3 * k + 1) * 64 + pl]);
    float offw = b2f(offm[(3 * k + 2) * 64 + pl]);
    float pd = (float)(d + (k / 9) - 1) + offd * 0.5f;
    float ph = (float)(h + ((k / 3) % 3) - 1) + offh;
    float pw = (float)(w + (k % 3) - 1) + offw;
    float fd = floorf(pd), fh = floorf(ph), fw = floorf(pw);
    float td = pd - fd, th = ph - fh, tw = pw - fw;
    int d0 = (int)fd, h0 = (int)fh, w0 = (int)fw;
    float mk = __expf(b2f(offm[(81 + k) * 64 + pl])) * rs;

    float wd0 = ((unsigned)d0 < (unsigned)Dn) ? (1.f - td) * mk : 0.f;
    float wd1 = ((unsigned)(d0 + 1) < (unsigned)Dn) ? td * mk : 0.f;
    float wh0 = ((unsigned)h0 < (unsigned)Hn) ? (1.f - th) : 0.f;
    float wh1 = ((unsigned)(h0 + 1) < (unsigned)Hn) ? th : 0.f;
    float ww0 = ((unsigned)w0 < (unsigned)Wn) ? (1.f - tw) : 0.f;
    float ww1 = ((unsigned)(w0 + 1) < (unsigned)Wn) ? tw : 0.f;
    int dr0 = iclamp(d0, 0, Dn - 1) * 4096, dr1 = iclamp(d0 + 1, 0, Dn - 1) * 4096;
    int hr0 = iclamp(h0, 0, Hn - 1) * 64,   hr1 = iclamp(h0 + 1, 0, Hn - 1) * 64;
    int wc0 = iclamp(w0, 0, Wn - 1),        wc1 = iclamp(w0 + 1, 0, Wn - 1);
    float wdh00 = wd0 * wh0, wdh01 = wd0 * wh1, wdh10 = wd1 * wh0, wdh11 = wd1 * wh1;

#define CORNER(RD, RH, WC, WT)                                          \
    {                                                                   \
      float wt_ = (WT);                                                 \
      f32x2 w2_ = {wt_, wt_};                                           \
      int boff_ = ((RD) + (RH) + (WC)) << 6;                            \
      uint4 ua_ = *(const uint4*)(vg + boff_);                          \
      acc[0] = FMA2(up2(ua_.x), w2_, acc[0]);                           \
      acc[1] = FMA2(up2(ua_.y), w2_, acc[1]);                           \
      acc[2] = FMA2(up2(ua_.z), w2_, acc[2]);                           \
      acc[3] = FMA2(up2(ua_.w), w2_, acc[3]);                           \
    }
    CORNER(dr0, hr0, wc0, wdh00 * ww0)
    CORNER(dr0, hr0, wc1, wdh00 * ww1)
    CORNER(dr0, hr1, wc0, wdh01 * ww0)
    CORNER(dr0, hr1, wc1, wdh01 * ww1)
    CORNER(dr1, hr0, wc0, wdh10 * ww0)
    CORNER(dr1, hr0, wc1, wdh10 * ww1)
    CORNER(dr1, hr1, wc0, wdh11 * ww0)
    CORNER(dr1, hr1, wc1, wdh11 * ww1)
#undef CORNER
  }

  const float* af = (const float*)acc;
  short8 o8;
#pragma unroll
  for (int j = 0; j < 8; ++j) o8[j] = f2b(af[j]);
  *(short8*)(sampled + ((size_t)bg * DHW + p) * GCn + q * 8) = o8;
}

// ---- out_proj: t (bf16, in ws) ----
__global__ __launch_bounds__(256) void outproj(
    const __hip_bfloat16* __restrict__ sampled, const float* __restrict__ Wout,
    const float* __restrict__ ob, __hip_bfloat16* __restrict__ t) {
  int p = blockIdx.x * 256 + threadIdx.x;
  int b = blockIdx.y;
  float sv[Cn];
#pragma unroll
  for (int g = 0; g < Gn; ++g) {
    const short8* src = (const short8*)(sampled) + ((size_t)(b * Gn + g) * DHW + p) * 4;
#pragma unroll
    for (int q = 0; q < 4; ++q) {
      short8 s8 = src[q];
#pragma unroll
      for (int j = 0; j < 8; ++j) sv[g * GCn + q * 8 + j] = b2f(s8[j]);
    }
  }
#pragma unroll 1
  for (int o = 0; o < Cn; ++o) {
    float s = ob[o];
#pragma unroll
    for (int c = 0; c < Cn; ++c) s += Wout[o * Cn + c] * sv[c];
    t[((size_t)b * Cn + o) * DHW + p] = __float2bfloat16(s);
  }
}

// ---- per-(b,c) instance-norm stats (bf16 input, vectorized) ----
__global__ __launch_bounds__(256) void stats_k(const __hip_bfloat16* __restrict__ t,
                                               float* __restrict__ stat) {
  int bc = blockIdx.x;
  const short8* tc = (const short8*)(t + (size_t)bc * DHW);
  float s = 0.f, ss = 0.f;
  for (int i = threadIdx.x; i < DHW / 8; i += 256) {
    short8 s8 = tc[i];
#pragma unroll
    for (int j = 0; j < 8; ++j) { float xv = b2f(s8[j]); s += xv; ss += xv * xv; }
  }
#pragma unroll
  for (int o = 32; o > 0; o >>= 1) { s += __shfl_down(s, o); ss += __shfl_down(ss, o); }
  __shared__ float ls[4], lss[4];
  int wid = threadIdx.x >> 6;
  if ((threadIdx.x & 63) == 0) { ls[wid] = s; lss[wid] = ss; }
  __syncthreads();
  if (threadIdx.x == 0) {
    float S = ls[0] + ls[1] + ls[2] + ls[3];
    float SS = lss[0] + lss[1] + lss[2] + lss[3];
    float mu = S / (float)DHW;
    float var = SS / (float)DHW - mu * mu;
    stat[bc * 2 + 0] = mu;
    stat[bc * 2 + 1] = rsqrtf(var + EPS);
  }
}

// ---- norm + gelu + post 1x1 + gated residual ----
__global__ __launch_bounds__(256) void finalk(
    const __hip_bfloat16* __restrict__ t, const float* __restrict__ x,
    const float* __restrict__ stat,
    const float* __restrict__ gamma, const float* __restrict__ beta,
    const float* __restrict__ Wpost, const float* __restrict__ gate, float* out) {
  int p = blockIdx.x * 256 + threadIdx.x;
  int b = blockIdx.y;
  float sg = 1.f / (1.f + __expf(-gate[0]));
  float nv[Cn];
#pragma unroll
  for (int c = 0; c < Cn; ++c) {
    float mu = stat[(b * Cn + c) * 2 + 0];
    float rstd = stat[(b * Cn + c) * 2 + 1];
    float tv = b2f(((const short*)t)[((size_t)b * Cn + c) * DHW + p]);
    float yv = (tv - mu) * rstd * gamma[c] + beta[c];
    float u = 0.7978845608028654f * (yv + 0.044715f * yv * yv * yv);
    float e = __expf(2.f * u);
    float th = 1.f - 2.f / (e + 1.f);
    nv[c] = 0.5f * yv * (1.f + th);
  }
#pragma unroll 1
  for (int o = 0; o < Cn; ++o) {
    float s = 0.f;
#pragma unroll
    for (int c = 0; c < Cn; ++c) s += Wpost[o * Cn + c] * nv[c];
    size_t i = ((size_t)b * Cn + o) * DHW + p;
    out[i] = x[i] + sg * s;
  }
}

extern "C" void kernel_launch(void* const* d_in, const int* in_sizes, int n_in,
                              void* d_out, int out_size, void* d_ws, size_t ws_size,
                              hipStream_t stream) {
  const float* x          = (const float*)d_in[0];
  const float* gate       = (const float*)d_in[1];
  const float* pre_w      = (const float*)d_in[2];
  const float* post_w     = (const float*)d_in[3];
  const float* in_proj_w  = (const float*)d_in[4];
  const float* in_proj_b  = (const float*)d_in[5];
  const float* out_proj_w = (const float*)d_in[6];
  const float* out_proj_b = (const float*)d_in[7];
  const float* off_w      = (const float*)d_in[8];
  const float* off_b      = (const float*)d_in[9];
  const float* mask_w     = (const float*)d_in[10];
  const float* mask_b     = (const float*)d_in[11];
  const float* in_gamma   = (const float*)d_in[12];
  const float* in_beta    = (const float*)d_in[13];

  char* ws = (char*)d_ws;
  __hip_bfloat16* xpadh = (__hip_bfloat16*)(ws + XPADH_OFF);
  short8* Wfrag  = (short8*)(ws + WFRAG_OFF);
  float* Wv      = (float*)(ws + WV_OFF);
  __hip_bfloat16* convout = (__hip_bfloat16*)(ws + CONV_OFF);
  __hip_bfloat16* v       = (__hip_bfloat16*)(ws + V_OFF);
  __hip_bfloat16* sampled = (__hip_bfloat16*)(ws + SAMP_OFF);
  float* stat    = (float*)(ws + STAT_OFF);
  __hip_bfloat16* t = (__hip_bfloat16*)(ws + XPADH_OFF);   // reuses xpadh region
  float* out = (float*)d_out;

  int zf16 = (int)(XPADH_B / 16);
  zerofill<<<(zf16 + 255) / 256, 256, 0, stream>>>((uint4*)xpadh, zf16);
  fillpad<<<dim3(DHW / 32, Bn), 256, 0, stream>>>(x, xpadh);
  int foldN = (64 * 64 + 54 * 16 * 64 + 255) / 256;
  fold_weights<<<foldN, 256, 0, stream>>>(pre_w, in_proj_w, off_w, mask_w, Wfrag, Wv);
  vproj<<<dim3(DHW / 256, Bn), 256, 0, stream>>>(x, Wv, in_proj_b, v);
  conv_mfma<<<dim3(32, 16, 2), 512, 0, stream>>>((const char*)xpadh, (const uint4*)Wfrag,
                                                 off_b, mask_b, convout);
  dcn_sample<<<dim3(DHW / 64, Bn * Gn), 256, 0, stream>>>(convout, v, sampled);
  outproj<<<dim3(DHW / 256, Bn), 256, 0, stream>>>(sampled, out_proj_w, out_proj_b, t);
  stats_k<<<Bn * Cn, 256, 0, stream>>>(t, stat);
  finalk<<<dim3(DHW / 256, Bn), 256, 0, stream>>>(t, x, stat, in_gamma, in_beta,
                                                  post_w, gate, out);
}